// Round 9
// baseline (622.877 us; speedup 1.0000x reference)
//
#include <hip/hip_runtime.h>

#define Bn 4
#define Cn 128
#define Nn 65536
#define KT 9
#define T_OUT 256
#define T_HALO 264
#define XROW 136        // f16 elems per LDS X row (128 + 8 pad) = 272 B
#define GROW 264        // f16 elems per LDS G row (control kernel layout)
#define FT 66           // f32 transpose-tile row stride (dwords)

typedef _Float16 f16x8 __attribute__((ext_vector_type(8)));
typedef _Float16 f16x4 __attribute__((ext_vector_type(4)));
typedef float f32x4 __attribute__((ext_vector_type(4)));
typedef float f32x2 __attribute__((ext_vector_type(2)));

// ---------------- repack weights: [O][C][K] f32 -> [t][o][c] f16 ----------------
__global__ __launch_bounds__(256) void repack_w(const float* __restrict__ w1,
                                                const float* __restrict__ w2,
                                                _Float16* __restrict__ Wr) {
  int i = blockIdx.x * 256 + threadIdx.x;  // [cv][t][o][c], total 2*9*128*128
  int c = i & 127;
  int o = (i >> 7) & 127;
  int t = (i >> 14) % KT;
  int cv = i / (KT << 14);
  const float* w = cv ? w2 : w1;
  Wr[i] = (_Float16)w[(o * 128 + c) * KT + t];
}

// ---------------- gather x into curve order, f16, channel-contiguous rows ------
__global__ __launch_bounds__(256) void gather_x(const float* __restrict__ x,
                                                const int* __restrict__ reidx,
                                                _Float16* __restrict__ xp) {
  __shared__ float ft[128 * FT];  // 33792 B
  int tid = threadIdx.x;
  int b = blockIdx.x >> 10;
  int n0 = (blockIdx.x & 1023) * 64;
  const float* xb = x + (size_t)b * Cn * Nn;
  {
    int cc = tid >> 4;
    int j4 = (tid & 15) * 4;
#pragma unroll
    for (int pass = 0; pass < 8; ++pass) {
      int c = pass * 16 + cc;
      f32x4 v = *(const f32x4*)(&xb[(size_t)c * Nn + n0 + j4]);
      *(f32x2*)(&ft[c * FT + j4]) = f32x2{v.x, v.y};
      *(f32x2*)(&ft[c * FT + j4 + 2]) = f32x2{v.z, v.w};
    }
  }
  __syncthreads();
  int ch = tid & 15;
  int rr = tid >> 4;
#pragma unroll
  for (int pass = 0; pass < 4; ++pass) {
    int r = pass * 16 + rr;
    int m = reidx[(size_t)b * Nn + n0 + r];
    f16x8 v;
#pragma unroll
    for (int k = 0; k < 8; ++k) v[k] = (_Float16)ft[(ch * 8 + k) * FT + r];
    *(f16x8*)(xp + ((size_t)b * Nn + m) * Cn + ch * 8) = v;
  }
}

// ---------------- fused: gather coords (LDS) + gaussian tap weights ------------
__global__ __launch_bounds__(256) void gather_g(const float* __restrict__ coords,
                                                const int* __restrict__ indices,
                                                float* __restrict__ G) {
  __shared__ float cx[264], cy[264], cz[264];
  int tid = threadIdx.x;
  int b = blockIdx.x >> 8;
  int n0 = (blockIdx.x & 255) * 256;
  const float* cb = coords + (size_t)b * 3 * Nn;
  for (int i = tid; i < 264; i += 256) {
    int q = n0 - 4 + i;
    q = q < 0 ? 0 : (q > Nn - 1 ? Nn - 1 : q);  // OOB value irrelevant (x==0 there)
    int idx = indices[(size_t)b * Nn + q];
    cx[i] = cb[idx];
    cy[i] = cb[Nn + idx];
    cz[i] = cb[2 * Nn + idx];
  }
  __syncthreads();
  int m = n0 + tid;
  float x0 = cx[tid + 4], y0 = cy[tid + 4], z0 = cz[tid + 4];
  float* Gb = G + (size_t)b * KT * Nn;
#pragma unroll
  for (int t = 0; t < KT; ++t) {
    float dx = cx[tid + t] - x0;
    float dy = cy[tid + t] - y0;
    float dz = cz[tid + t] - z0;
    Gb[(size_t)t * Nn + m] = __expf(-(dx * dx + dy * dy + dz * dz));  // sigma=1
  }
}

// ---------------- BN affine coefficients ---------------------------------------
__global__ void bncoeff(const float* __restrict__ sums,
                        const float* __restrict__ gamma,
                        const float* __restrict__ beta,
                        float* __restrict__ coeff) {
  int c = threadIdx.x;  // 128 threads
  const float inv = 1.0f / (float)((size_t)Bn * Nn);
  float mean = sums[c] * inv;
  float var = sums[128 + c] * inv - mean * mean;
  float a = gamma[c] * rsqrtf(var + 1e-5f);
  coeff[c] = a;
  coeff[128 + c] = beta[c] - mean * a;
}

__device__ __forceinline__ f16x8 scale8(f16x8 v, _Float16 g) {
  f16x8 r;
#pragma unroll
  for (int i = 0; i < 8; ++i) r[i] = v[i] * g;  // 4x v_pk_mul_f16
  return r;
}

// ================= conv variant A (control, r0-exact): 256 thr, 4 waves ========
// Per-wave M64 x N128 (128 AGPR acc), 2 waves/SIMD. Measured 150us.
template <int TRANS>
__global__ __launch_bounds__(256, 2) void conv_mfma(
    const _Float16* __restrict__ Xin, const _Float16* __restrict__ W,
    const float* __restrict__ G, _Float16* __restrict__ Yout,
    float* __restrict__ sums, const float* __restrict__ coeff) {
  __shared__ __align__(16) _Float16 Xs[T_HALO * XROW];  // 71808 B
  __shared__ __align__(16) unsigned char aux[KT * GROW * 2];  // 4752 B: Gs, later red
  _Float16* Gs = (_Float16*)aux;
  float* red = (float*)aux;

  const int tid = threadIdx.x;
  const int b = blockIdx.x >> 8;
  const int p0 = (blockIdx.x & 255) * T_OUT;
  const int ch = tid & 15;

#pragma unroll
  for (int pass = 0; pass < 17; ++pass) {
    int r = pass * 16 + (tid >> 4);
    if (r < T_HALO) {
      int q = p0 - 4 + r;
      f16x8 v = {0, 0, 0, 0, 0, 0, 0, 0};
      if (q >= 0 && q < Nn) {
        v = *(const f16x8*)(Xin + ((size_t)b * Nn + q) * Cn + ch * 8);
        if (TRANS) {
#pragma unroll
          for (int i = 0; i < 8; ++i) {
            float f = fmaxf(coeff[ch * 8 + i] * (float)v[i] + coeff[128 + ch * 8 + i], 0.f);
            v[i] = (_Float16)f;
          }
        }
      }
      *(f16x8*)(&Xs[r * XROW + ch * 8]) = v;
    }
  }
  {
    const float* gb = G + (size_t)b * KT * Nn + p0;
    for (int i = tid; i < KT * 256; i += 256) {
      int t = i >> 8;
      int p = i & 255;
      Gs[t * GROW + p] = (_Float16)gb[(size_t)t * Nn + p];
    }
  }

  const int w = tid >> 6;
  const int lane = tid & 63;
  const int l15 = lane & 15;
  const int quad = lane >> 4;
  const int wm = w >> 1;
  const int wn = w & 1;

  f32x4 acc[4][8];
  const f32x4 z4 = {0.f, 0.f, 0.f, 0.f};
#pragma unroll
  for (int mt = 0; mt < 4; ++mt)
#pragma unroll
    for (int nt = 0; nt < 8; ++nt) acc[mt][nt] = z4;

  __syncthreads();

#pragma unroll 1
  for (int t = 0; t < KT; ++t) {
    _Float16 gt[8];
#pragma unroll
    for (int nt = 0; nt < 8; ++nt)
      gt[nt] = Gs[t * GROW + wn * 128 + nt * 16 + l15];

    const _Float16* Wt = W + ((size_t)t << 14) + (wm * 64) * Cn;
#pragma unroll
    for (int ko = 0; ko < 4; ++ko) {
      f16x8 a[4];
#pragma unroll
      for (int mt = 0; mt < 4; ++mt)
        a[mt] = *(const f16x8*)(Wt + (mt * 16 + l15) * Cn + ko * 32 + quad * 8);
#pragma unroll
      for (int nt = 0; nt < 8; ++nt) {
        f16x8 bv = *(const f16x8*)(&Xs[(wn * 128 + nt * 16 + l15 + t) * XROW + ko * 32 + quad * 8]);
        bv = scale8(bv, gt[nt]);
#pragma unroll
        for (int mt = 0; mt < 4; ++mt)
          acc[mt][nt] = __builtin_amdgcn_mfma_f32_16x16x32_f16(a[mt], bv, acc[mt][nt], 0, 0, 0);
      }
    }
  }

  f32x4 s4[4], q4[4];
#pragma unroll
  for (int mt = 0; mt < 4; ++mt) {
#pragma unroll
    for (int rg = 0; rg < 4; ++rg) {
      float s = 0.f, q = 0.f;
#pragma unroll
      for (int nt = 0; nt < 8; ++nt) {
        float v = acc[mt][nt][rg];
        s += v;
        q += v * v;
      }
#pragma unroll
      for (int m = 1; m < 16; m <<= 1) {
        s += __shfl_xor(s, m);
        q += __shfl_xor(q, m);
      }
      s4[mt][rg] = s;
      q4[mt][rg] = q;
    }
  }
  __syncthreads();
  if (l15 == 0) {
#pragma unroll
    for (int mt = 0; mt < 4; ++mt) {
      int cbase = wm * 64 + mt * 16 + quad * 4;
      *(f32x4*)(&red[wn * 128 + cbase]) = s4[mt];
      *(f32x4*)(&red[256 + wn * 128 + cbase]) = q4[mt];
    }
  }

  _Float16* Os = Xs;
#pragma unroll
  for (int mt = 0; mt < 4; ++mt)
#pragma unroll
    for (int nt = 0; nt < 8; ++nt) {
      f16x4 o4;
#pragma unroll
      for (int rg = 0; rg < 4; ++rg) o4[rg] = (_Float16)acc[mt][nt][rg];
      *(f16x4*)(&Os[(wn * 128 + nt * 16 + l15) * XROW + wm * 64 + mt * 16 + quad * 4]) = o4;
    }
  __syncthreads();

  if (tid < 128) {
    atomicAdd(&sums[tid], red[tid] + red[128 + tid]);
    atomicAdd(&sums[128 + tid], red[256 + tid] + red[384 + tid]);
  }
#pragma unroll
  for (int pass = 0; pass < 16; ++pass) {
    int r = pass * 16 + (tid >> 4);
    f16x8 v = *(const f16x8*)(&Os[r * XROW + ch * 8]);
    *(f16x8*)(Yout + ((size_t)b * Nn + p0 + r) * Cn + ch * 8) = v;
  }
}

// ================= conv variant B (experiment): 512 thr, ILP headroom ==========
// Same T_OUT=256 tile; waves 2(M)x4(N), per-wave M64 x N64 (64 AGPR acc).
// launch_bounds(512,2): register cap 256 -> ~190 arch VGPRs of scheduling
// headroom (r0 was pinned at 128; r8's (512,4) cap forced 64 arch -> spills).
// Hypothesis: more arch regs => compiler pipelines the B-fragment ds_reads
// several iterations deep, hiding the ds_read->pk_mul->MFMA chain at fixed TLP.
// Also: Gs stored transposed [t][wn][l15][nt] so each lane's 4 per-tap gaussian
// scalars are ONE ds_read_b64 (was 8 scalar ds_read_u16 per tap in control).
template <int TRANS>
__global__ __launch_bounds__(512, 2) void conv_mfma8(
    const _Float16* __restrict__ Xin, const _Float16* __restrict__ W,
    const float* __restrict__ G, _Float16* __restrict__ Yout,
    float* __restrict__ sums, const float* __restrict__ coeff) {
  __shared__ __align__(16) _Float16 Xs[T_HALO * XROW];  // 71808 B
  __shared__ __align__(16) unsigned char aux[KT * GROW * 2];  // 4752 B
  _Float16* Gs = (_Float16*)aux;   // transposed: [(t*4+wn)*16+l15]*4+nt, 4608 B
  float* red = (float*)aux;        // later: s [0,512) q [512,1024) f32

  const int tid = threadIdx.x;
  const int b = blockIdx.x >> 8;
  const int p0 = (blockIdx.x & 255) * T_OUT;
  const int ch = tid & 15;

  // ---- stage X halo tile: 512 threads, 32 rows/pass ----
#pragma unroll
  for (int pass = 0; pass < 9; ++pass) {
    int r = pass * 32 + (tid >> 4);
    if (r < T_HALO) {
      int q = p0 - 4 + r;
      f16x8 v = {0, 0, 0, 0, 0, 0, 0, 0};
      if (q >= 0 && q < Nn) {
        v = *(const f16x8*)(Xin + ((size_t)b * Nn + q) * Cn + ch * 8);
        if (TRANS) {
#pragma unroll
          for (int i = 0; i < 8; ++i) {
            float f = fmaxf(coeff[ch * 8 + i] * (float)v[i] + coeff[128 + ch * 8 + i], 0.f);
            v[i] = (_Float16)f;
          }
        }
      }
      *(f16x8*)(&Xs[r * XROW + ch * 8]) = v;
    }
  }
  // ---- stage G transposed: lane-contiguous per-tap scalars ----
  {
    const float* gb = G + (size_t)b * KT * Nn + p0;
    for (int i = tid; i < KT * 256; i += 512) {
      int t = i >> 8;
      int p = i & 255;
      int wn_ = p >> 6, nt_ = (p >> 4) & 3, l_ = p & 15;
      Gs[((t * 4 + wn_) * 16 + l_) * 4 + nt_] = (_Float16)gb[(size_t)t * Nn + p];
    }
  }

  const int w = tid >> 6;        // 0..7
  const int lane = tid & 63;
  const int l15 = lane & 15;
  const int quad = lane >> 4;
  const int wm = w >> 2;         // 0..1: channels wm*64..+63
  const int wn = w & 3;          // 0..3: positions wn*64..+63

  f32x4 acc[4][4];
  const f32x4 z4 = {0.f, 0.f, 0.f, 0.f};
#pragma unroll
  for (int mt = 0; mt < 4; ++mt)
#pragma unroll
    for (int nt = 0; nt < 4; ++nt) acc[mt][nt] = z4;

  __syncthreads();

#pragma unroll 1
  for (int t = 0; t < KT; ++t) {
    f16x4 gt4 = *(const f16x4*)(&Gs[((t * 4 + wn) * 16 + l15) * 4]);  // 1 ds_read_b64

    const _Float16* Wt = W + ((size_t)t << 14) + (wm * 64) * Cn;
#pragma unroll
    for (int ko = 0; ko < 4; ++ko) {
      f16x8 a4[4];
#pragma unroll
      for (int mt = 0; mt < 4; ++mt)
        a4[mt] = *(const f16x8*)(Wt + (mt * 16 + l15) * Cn + ko * 32 + quad * 8);
#pragma unroll
      for (int nt = 0; nt < 4; ++nt) {
        f16x8 bv = *(const f16x8*)(&Xs[(wn * 64 + nt * 16 + l15 + t) * XROW + ko * 32 + quad * 8]);
        bv = scale8(bv, gt4[nt]);
#pragma unroll
        for (int mt = 0; mt < 4; ++mt)
          acc[mt][nt] = __builtin_amdgcn_mfma_f32_16x16x32_f16(a4[mt], bv, acc[mt][nt], 0, 0, 0);
      }
    }
  }

  // ---- BN partial sums ----
  f32x4 s4[4], q4[4];
#pragma unroll
  for (int mt = 0; mt < 4; ++mt) {
#pragma unroll
    for (int rg = 0; rg < 4; ++rg) {
      float s = 0.f, q = 0.f;
#pragma unroll
      for (int nt = 0; nt < 4; ++nt) {
        float v = acc[mt][nt][rg];
        s += v;
        q += v * v;
      }
#pragma unroll
      for (int m = 1; m < 16; m <<= 1) {
        s += __shfl_xor(s, m);
        q += __shfl_xor(q, m);
      }
      s4[mt][rg] = s;
      q4[mt][rg] = q;
    }
  }
  __syncthreads();
  if (l15 == 0) {
#pragma unroll
    for (int mt = 0; mt < 4; ++mt) {
      int cbase = wm * 64 + mt * 16 + quad * 4;
      *(f32x4*)(&red[wn * 128 + cbase]) = s4[mt];         // s: [0,512)
      *(f32x4*)(&red[512 + wn * 128 + cbase]) = q4[mt];   // q: [512,1024)
    }
  }

  // ---- epilogue transpose ----
  _Float16* Os = Xs;
#pragma unroll
  for (int mt = 0; mt < 4; ++mt)
#pragma unroll
    for (int nt = 0; nt < 4; ++nt) {
      f16x4 o4;
#pragma unroll
      for (int rg = 0; rg < 4; ++rg) o4[rg] = (_Float16)acc[mt][nt][rg];
      *(f16x4*)(&Os[(wn * 64 + nt * 16 + l15) * XROW + wm * 64 + mt * 16 + quad * 4]) = o4;
    }
  __syncthreads();

  if (tid < 128) {
    atomicAdd(&sums[tid],
              red[tid] + red[128 + tid] + red[256 + tid] + red[384 + tid]);
    atomicAdd(&sums[128 + tid],
              red[512 + tid] + red[640 + tid] + red[768 + tid] + red[896 + tid]);
  }
#pragma unroll
  for (int pass = 0; pass < 8; ++pass) {
    int r = pass * 32 + (tid >> 4);
    f16x8 v = *(const f16x8*)(&Os[r * XROW + ch * 8]);
    *(f16x8*)(Yout + ((size_t)b * Nn + p0 + r) * Cn + ch * 8) = v;
  }
}

// ---------------- final: scatter + BN2 affine + residual + relu ----------------
__global__ __launch_bounds__(256) void final_k(const _Float16* __restrict__ y2,
                                               const float* __restrict__ x,
                                               const int* __restrict__ reidx,
                                               const float* __restrict__ coeff,
                                               float* __restrict__ out) {
  __shared__ float ft[128 * FT];  // 33792 B
  int tid = threadIdx.x;
  int b = blockIdx.x >> 10;
  int n0 = (blockIdx.x & 1023) * 64;
  {
    int ch = tid & 15;
#pragma unroll
    for (int pass = 0; pass < 4; ++pass) {
      int r = pass * 16 + (tid >> 4);
      int m = reidx[(size_t)b * Nn + n0 + r];
      f16x8 v = *(const f16x8*)(y2 + ((size_t)b * Nn + m) * Cn + ch * 8);
#pragma unroll
      for (int k = 0; k < 8; ++k) ft[(ch * 8 + k) * FT + r] = (float)v[k];
    }
  }
  __syncthreads();
  int cc = tid >> 4;
  int j4 = (tid & 15) * 4;
#pragma unroll
  for (int pass = 0; pass < 8; ++pass) {
    int c = pass * 16 + cc;
    float a = coeff[c];
    float bb = coeff[128 + c];
    f32x2 v0 = *(const f32x2*)(&ft[c * FT + j4]);
    f32x2 v1 = *(const f32x2*)(&ft[c * FT + j4 + 2]);
    size_t gi = ((size_t)b * Cn + c) * Nn + n0 + j4;
    f32x4 xv = *(const f32x4*)(&x[gi]);
    f32x4 r;
    r.x = fmaxf(a * v0.x + bb + xv.x, 0.f);
    r.y = fmaxf(a * v0.y + bb + xv.y, 0.f);
    r.z = fmaxf(a * v1.x + bb + xv.z, 0.f);
    r.w = fmaxf(a * v1.y + bb + xv.w, 0.f);
    *(f32x4*)(&out[gi]) = r;
  }
}

extern "C" void kernel_launch(void* const* d_in, const int* in_sizes, int n_in,
                              void* d_out, int out_size, void* d_ws, size_t ws_size,
                              hipStream_t stream) {
  (void)in_sizes; (void)n_in; (void)out_size; (void)ws_size;
  const float* x = (const float*)d_in[0];
  const float* coords = (const float*)d_in[1];
  const int* indices = (const int*)d_in[2];
  const int* reindices = (const int*)d_in[3];
  const float* w1 = (const float*)d_in[4];
  const float* gamma1 = (const float*)d_in[5];
  const float* beta1 = (const float*)d_in[6];
  const float* w2 = (const float*)d_in[7];
  const float* gamma2 = (const float*)d_in[8];
  const float* beta2 = (const float*)d_in[9];
  float* out = (float*)d_out;

  // workspace: [0,64MB) xp -> y2 ; then sums1/sums2/coeff1/coeff2 ; then Wr f16
  char* ws = (char*)d_ws;
  const size_t BUF0 = (size_t)Bn * Nn * Cn * sizeof(_Float16);  // 64 MB
  _Float16* buf0 = (_Float16*)ws;
  float* sums1 = (float*)(ws + BUF0);
  float* sums2 = sums1 + 256;
  float* coeff1 = sums1 + 512;
  float* coeff2 = sums1 + 768;
  _Float16* Wr = (_Float16*)(ws + BUF0 + 4096);  // 2*9*128*128 f16 = 576 KB

  // d_out doubles as scratch until the final kernel: y1 f16 [0,64MB), G
  char* dob = (char*)d_out;
  _Float16* y1 = (_Float16*)dob;
  float* G = (float*)(dob + BUF0);  // 9 MB

  hipMemsetAsync(sums1, 0, 512 * sizeof(float), stream);

  repack_w<<<1152, 256, 0, stream>>>(w1, w2, Wr);
  gather_x<<<Bn * 1024, 256, 0, stream>>>(x, reindices, buf0);
  gather_g<<<Bn * 256, 256, 0, stream>>>(coords, indices, G);

  // A/B: conv1 = 512-thr ILP-headroom experiment, conv2 = r0-exact control
  conv_mfma8<0><<<Bn * 256, 512, 0, stream>>>(buf0, Wr, G, y1, sums1, nullptr);
  bncoeff<<<1, 128, 0, stream>>>(sums1, gamma1, beta1, coeff1);
  conv_mfma<1><<<Bn * 256, 256, 0, stream>>>(y1, Wr + (size_t)KT * Cn * Cn, G,
                                             buf0, sums2, coeff1);
  bncoeff<<<1, 128, 0, stream>>>(sums2, gamma2, beta2, coeff2);
  final_k<<<Bn * 1024, 256, 0, stream>>>(buf0, x, reindices, coeff2, out);
}

// Round 10
// 555.857 us; speedup vs baseline: 1.1206x; 1.1206x over previous
//
#include <hip/hip_runtime.h>

#define Bn 4
#define Cn 128
#define Nn 65536
#define KT 9
#define T_OUT 256
#define T_HALO 264
#define XROW 136        // f16 elems per LDS row (128 + 8 pad) = 272 B
#define GROW 264        // f16 elems per LDS G row
#define FT 66           // f32 transpose-tile row stride (dwords)

typedef _Float16 f16x8 __attribute__((ext_vector_type(8)));
typedef _Float16 f16x4 __attribute__((ext_vector_type(4)));
typedef float f32x4 __attribute__((ext_vector_type(4)));
typedef float f32x2 __attribute__((ext_vector_type(2)));

// ---------------- repack weights: [O][C][K] f32 -> [t][o][c] f16 ----------------
__global__ __launch_bounds__(256) void repack_w(const float* __restrict__ w1,
                                                const float* __restrict__ w2,
                                                _Float16* __restrict__ Wr) {
  int i = blockIdx.x * 256 + threadIdx.x;  // [cv][t][o][c], total 2*9*128*128
  int c = i & 127;
  int o = (i >> 7) & 127;
  int t = (i >> 14) % KT;
  int cv = i / (KT << 14);
  const float* w = cv ? w2 : w1;
  Wr[i] = (_Float16)w[(o * 128 + c) * KT + t];
}

// ---------------- gather x into curve order, f16, channel-contiguous rows ------
__global__ __launch_bounds__(256) void gather_x(const float* __restrict__ x,
                                                const int* __restrict__ reidx,
                                                _Float16* __restrict__ xp) {
  __shared__ float ft[128 * FT];  // 33792 B
  int tid = threadIdx.x;
  int b = blockIdx.x >> 10;
  int n0 = (blockIdx.x & 1023) * 64;
  const float* xb = x + (size_t)b * Cn * Nn;
  {
    int cc = tid >> 4;
    int j4 = (tid & 15) * 4;
#pragma unroll
    for (int pass = 0; pass < 8; ++pass) {
      int c = pass * 16 + cc;
      f32x4 v = *(const f32x4*)(&xb[(size_t)c * Nn + n0 + j4]);
      *(f32x2*)(&ft[c * FT + j4]) = f32x2{v.x, v.y};
      *(f32x2*)(&ft[c * FT + j4 + 2]) = f32x2{v.z, v.w};
    }
  }
  __syncthreads();
  int ch = tid & 15;
  int rr = tid >> 4;
#pragma unroll
  for (int pass = 0; pass < 4; ++pass) {
    int r = pass * 16 + rr;
    int m = reidx[(size_t)b * Nn + n0 + r];
    f16x8 v;
#pragma unroll
    for (int k = 0; k < 8; ++k) v[k] = (_Float16)ft[(ch * 8 + k) * FT + r];
    *(f16x8*)(xp + ((size_t)b * Nn + m) * Cn + ch * 8) = v;
  }
}

// ---------------- fused: gather coords (LDS) + gaussian tap weights ------------
__global__ __launch_bounds__(256) void gather_g(const float* __restrict__ coords,
                                                const int* __restrict__ indices,
                                                float* __restrict__ G) {
  __shared__ float cx[264], cy[264], cz[264];
  int tid = threadIdx.x;
  int b = blockIdx.x >> 8;
  int n0 = (blockIdx.x & 255) * 256;
  const float* cb = coords + (size_t)b * 3 * Nn;
  for (int i = tid; i < 264; i += 256) {
    int q = n0 - 4 + i;
    q = q < 0 ? 0 : (q > Nn - 1 ? Nn - 1 : q);  // OOB value irrelevant (x==0 there)
    int idx = indices[(size_t)b * Nn + q];
    cx[i] = cb[idx];
    cy[i] = cb[Nn + idx];
    cz[i] = cb[2 * Nn + idx];
  }
  __syncthreads();
  int m = n0 + tid;
  float x0 = cx[tid + 4], y0 = cy[tid + 4], z0 = cz[tid + 4];
  float* Gb = G + (size_t)b * KT * Nn;
#pragma unroll
  for (int t = 0; t < KT; ++t) {
    float dx = cx[tid + t] - x0;
    float dy = cy[tid + t] - y0;
    float dz = cz[tid + t] - z0;
    Gb[(size_t)t * Nn + m] = __expf(-(dx * dx + dy * dy + dz * dz));  // sigma=1
  }
}

// ---------------- BN affine coefficients ---------------------------------------
__global__ void bncoeff(const float* __restrict__ sums,
                        const float* __restrict__ gamma,
                        const float* __restrict__ beta,
                        float* __restrict__ coeff) {
  int c = threadIdx.x;  // 128 threads
  const float inv = 1.0f / (float)((size_t)Bn * Nn);
  float mean = sums[c] * inv;
  float var = sums[128 + c] * inv - mean * mean;
  float a = gamma[c] * rsqrtf(var + 1e-5f);
  coeff[c] = a;
  coeff[128 + c] = beta[c] - mean * a;
}

__device__ __forceinline__ f16x8 scale8(f16x8 v, _Float16 g) {
  f16x8 r;
#pragma unroll
  for (int i = 0; i < 8; ++i) r[i] = v[i] * g;  // 4x v_pk_mul_f16
  return r;
}

// ================= conv variant A (control, r0-exact): 256 thr, 4 waves ========
// Per-wave M64 x N128 (128 AGPR acc), 2 waves/SIMD. Measured 150us.
template <int TRANS>
__global__ __launch_bounds__(256, 2) void conv_mfma(
    const _Float16* __restrict__ Xin, const _Float16* __restrict__ W,
    const float* __restrict__ G, _Float16* __restrict__ Yout,
    float* __restrict__ sums, const float* __restrict__ coeff) {
  __shared__ __align__(16) _Float16 Xs[T_HALO * XROW];  // 71808 B
  __shared__ __align__(16) unsigned char aux[KT * GROW * 2];  // 4752 B: Gs, later red
  _Float16* Gs = (_Float16*)aux;
  float* red = (float*)aux;

  const int tid = threadIdx.x;
  const int b = blockIdx.x >> 8;
  const int p0 = (blockIdx.x & 255) * T_OUT;
  const int ch = tid & 15;

#pragma unroll
  for (int pass = 0; pass < 17; ++pass) {
    int r = pass * 16 + (tid >> 4);
    if (r < T_HALO) {
      int q = p0 - 4 + r;
      f16x8 v = {0, 0, 0, 0, 0, 0, 0, 0};
      if (q >= 0 && q < Nn) {
        v = *(const f16x8*)(Xin + ((size_t)b * Nn + q) * Cn + ch * 8);
        if (TRANS) {
#pragma unroll
          for (int i = 0; i < 8; ++i) {
            float f = fmaxf(coeff[ch * 8 + i] * (float)v[i] + coeff[128 + ch * 8 + i], 0.f);
            v[i] = (_Float16)f;
          }
        }
      }
      *(f16x8*)(&Xs[r * XROW + ch * 8]) = v;
    }
  }
  {
    const float* gb = G + (size_t)b * KT * Nn + p0;
    for (int i = tid; i < KT * 256; i += 256) {
      int t = i >> 8;
      int p = i & 255;
      Gs[t * GROW + p] = (_Float16)gb[(size_t)t * Nn + p];
    }
  }

  const int w = tid >> 6;
  const int lane = tid & 63;
  const int l15 = lane & 15;
  const int quad = lane >> 4;
  const int wm = w >> 1;
  const int wn = w & 1;

  f32x4 acc[4][8];
  const f32x4 z4 = {0.f, 0.f, 0.f, 0.f};
#pragma unroll
  for (int mt = 0; mt < 4; ++mt)
#pragma unroll
    for (int nt = 0; nt < 8; ++nt) acc[mt][nt] = z4;

  __syncthreads();

#pragma unroll 1
  for (int t = 0; t < KT; ++t) {
    _Float16 gt[8];
#pragma unroll
    for (int nt = 0; nt < 8; ++nt)
      gt[nt] = Gs[t * GROW + wn * 128 + nt * 16 + l15];

    const _Float16* Wt = W + ((size_t)t << 14) + (wm * 64) * Cn;
#pragma unroll
    for (int ko = 0; ko < 4; ++ko) {
      f16x8 a[4];
#pragma unroll
      for (int mt = 0; mt < 4; ++mt)
        a[mt] = *(const f16x8*)(Wt + (mt * 16 + l15) * Cn + ko * 32 + quad * 8);
#pragma unroll
      for (int nt = 0; nt < 8; ++nt) {
        f16x8 bv = *(const f16x8*)(&Xs[(wn * 128 + nt * 16 + l15 + t) * XROW + ko * 32 + quad * 8]);
        bv = scale8(bv, gt[nt]);
#pragma unroll
        for (int mt = 0; mt < 4; ++mt)
          acc[mt][nt] = __builtin_amdgcn_mfma_f32_16x16x32_f16(a[mt], bv, acc[mt][nt], 0, 0, 0);
      }
    }
  }

  f32x4 s4[4], q4[4];
#pragma unroll
  for (int mt = 0; mt < 4; ++mt) {
#pragma unroll
    for (int rg = 0; rg < 4; ++rg) {
      float s = 0.f, q = 0.f;
#pragma unroll
      for (int nt = 0; nt < 8; ++nt) {
        float v = acc[mt][nt][rg];
        s += v;
        q += v * v;
      }
#pragma unroll
      for (int m = 1; m < 16; m <<= 1) {
        s += __shfl_xor(s, m);
        q += __shfl_xor(q, m);
      }
      s4[mt][rg] = s;
      q4[mt][rg] = q;
    }
  }
  __syncthreads();
  if (l15 == 0) {
#pragma unroll
    for (int mt = 0; mt < 4; ++mt) {
      int cbase = wm * 64 + mt * 16 + quad * 4;
      *(f32x4*)(&red[wn * 128 + cbase]) = s4[mt];
      *(f32x4*)(&red[256 + wn * 128 + cbase]) = q4[mt];
    }
  }

  _Float16* Os = Xs;
#pragma unroll
  for (int mt = 0; mt < 4; ++mt)
#pragma unroll
    for (int nt = 0; nt < 8; ++nt) {
      f16x4 o4;
#pragma unroll
      for (int rg = 0; rg < 4; ++rg) o4[rg] = (_Float16)acc[mt][nt][rg];
      *(f16x4*)(&Os[(wn * 128 + nt * 16 + l15) * XROW + wm * 64 + mt * 16 + quad * 4]) = o4;
    }
  __syncthreads();

  if (tid < 128) {
    atomicAdd(&sums[tid], red[tid] + red[128 + tid]);
    atomicAdd(&sums[128 + tid], red[256 + tid] + red[384 + tid]);
  }
#pragma unroll
  for (int pass = 0; pass < 16; ++pass) {
    int r = pass * 16 + (tid >> 4);
    f16x8 v = *(const f16x8*)(&Os[r * XROW + ch * 8]);
    *(f16x8*)(Yout + ((size_t)b * Nn + p0 + r) * Cn + ch * 8) = v;
  }
}

// ================= conv variant B (experiment): pure-LDS K-loop ================
// m97-structure port: W staged per-tap into LDS (double-buffered, padded rows)
// so the K-loop issues ONLY ds_read/lgkmcnt ops (no vmcnt in the MFMA ladder).
// Prefetch tap t+2's W to regs at iteration top (latency hidden under compute),
// one barrier per tap, ds_write after the barrier. 512 thr = 8 waves (2/SIMD),
// waves 4(M)x2(N), per-wave M32 x N128: keeps A-reuse=8 of the winning tile,
// acc = 64 AGPR. LDS 146 KB -> 1 block/CU (m201 precedent: 1-block/CU works).
__global__ __launch_bounds__(512) void conv_wlds(
    const _Float16* __restrict__ Xin, const _Float16* __restrict__ W,
    const float* __restrict__ G, _Float16* __restrict__ Yout,
    float* __restrict__ sums) {
  __shared__ __align__(16) _Float16 Xs[T_HALO * XROW];       // 71808 B
  __shared__ __align__(16) _Float16 Wlds[2][128 * XROW];     // 2 x 34816 B
  __shared__ __align__(16) unsigned char aux[KT * GROW * 2]; // 4752 B: Gs / red
  _Float16* Gs = (_Float16*)aux;
  float* red = (float*)aux;

  const int tid = threadIdx.x;
  const int b = blockIdx.x >> 8;
  const int p0 = (blockIdx.x & 255) * T_OUT;
  const int ch = tid & 15;

  // ---- issue W0/W1 prefetch first (flies during X staging) ----
  f16x8 w0r[4], w1r[4];
#pragma unroll
  for (int i = 0; i < 4; ++i) {
    int q = i * 512 + tid;  // 16B chunk id, 2048 per tap
    w0r[i] = *(const f16x8*)(W + (q >> 4) * 128 + (q & 15) * 8);
    w1r[i] = *(const f16x8*)(W + 16384 + (q >> 4) * 128 + (q & 15) * 8);
  }

  // ---- stage X halo tile (512 thr: 32 rows/pass) ----
#pragma unroll
  for (int pass = 0; pass < 9; ++pass) {
    int r = pass * 32 + (tid >> 4);
    if (r < T_HALO) {
      int q = p0 - 4 + r;
      f16x8 v = {0, 0, 0, 0, 0, 0, 0, 0};
      if (q >= 0 && q < Nn)
        v = *(const f16x8*)(Xin + ((size_t)b * Nn + q) * Cn + ch * 8);
      *(f16x8*)(&Xs[r * XROW + ch * 8]) = v;
    }
  }
  // ---- stage G ----
  {
    const float* gb = G + (size_t)b * KT * Nn + p0;
    for (int i = tid; i < KT * 256; i += 512) {
      int t = i >> 8;
      int p = i & 255;
      Gs[t * GROW + p] = (_Float16)gb[(size_t)t * Nn + p];
    }
  }
  // ---- write W0/W1 into padded LDS rows ----
#pragma unroll
  for (int i = 0; i < 4; ++i) {
    int q = i * 512 + tid;
    *(f16x8*)(&Wlds[0][(q >> 4) * XROW + (q & 15) * 8]) = w0r[i];
    *(f16x8*)(&Wlds[1][(q >> 4) * XROW + (q & 15) * 8]) = w1r[i];
  }

  const int w = tid >> 6;        // 0..7
  const int lane = tid & 63;
  const int l15 = lane & 15;
  const int quad = lane >> 4;
  const int wm = w >> 1;         // 0..3: channels wm*32 .. +31
  const int wn = w & 1;          // 0..1: positions wn*128 .. +127

  f32x4 acc[2][8];
  const f32x4 z4 = {0.f, 0.f, 0.f, 0.f};
#pragma unroll
  for (int mt = 0; mt < 2; ++mt)
#pragma unroll
    for (int nt = 0; nt < 8; ++nt) acc[mt][nt] = z4;

  __syncthreads();

  // ---- K-loop: pure-LDS ladder; W dbuf with reg prefetch of tap t+2 ----
  f16x8 wpre[4];
#pragma unroll 1
  for (int t = 0; t < KT; ++t) {
    if (t <= KT - 3) {
      const _Float16* Wt2 = W + ((size_t)(t + 2) << 14);
#pragma unroll
      for (int i = 0; i < 4; ++i) {
        int q = i * 512 + tid;
        wpre[i] = *(const f16x8*)(Wt2 + (q >> 4) * 128 + (q & 15) * 8);
      }
    }

    _Float16 gt[8];
#pragma unroll
    for (int nt = 0; nt < 8; ++nt)
      gt[nt] = Gs[t * GROW + wn * 128 + nt * 16 + l15];

    const _Float16* Wb = &Wlds[t & 1][0];
#pragma unroll
    for (int ko = 0; ko < 4; ++ko) {
      f16x8 a2[2];
#pragma unroll
      for (int mt = 0; mt < 2; ++mt)
        a2[mt] = *(const f16x8*)(Wb + (wm * 32 + mt * 16 + l15) * XROW + ko * 32 + quad * 8);
#pragma unroll
      for (int nt = 0; nt < 8; ++nt) {
        f16x8 bv = *(const f16x8*)(&Xs[(wn * 128 + nt * 16 + l15 + t) * XROW + ko * 32 + quad * 8]);
        bv = scale8(bv, gt[nt]);
#pragma unroll
        for (int mt = 0; mt < 2; ++mt)
          acc[mt][nt] = __builtin_amdgcn_mfma_f32_16x16x32_f16(a2[mt], bv, acc[mt][nt], 0, 0, 0);
      }
    }

    __syncthreads();  // all waves done reading Wlds[t&1]; prefetch loads drained
    if (t <= KT - 3) {
#pragma unroll
      for (int i = 0; i < 4; ++i) {
        int q = i * 512 + tid;
        *(f16x8*)(&Wlds[t & 1][(q >> 4) * XROW + (q & 15) * 8]) = wpre[i];
      }
    }
    // tap t+1 reads Wlds[(t+1)&1] (untouched); tap t+2's reads happen after
    // barrier(t+1), which makes these writes visible. No extra barrier needed.
  }

  // ---- BN partial sums (shfl tree over l15) ----
  // channel of acc[mt][*][rg] = wm*32 + mt*16 + quad*4 + rg
  f32x4 s4[2], q4[2];
#pragma unroll
  for (int mt = 0; mt < 2; ++mt) {
#pragma unroll
    for (int rg = 0; rg < 4; ++rg) {
      float s = 0.f, q = 0.f;
#pragma unroll
      for (int nt = 0; nt < 8; ++nt) {
        float v = acc[mt][nt][rg];
        s += v;
        q += v * v;
      }
#pragma unroll
      for (int m = 1; m < 16; m <<= 1) {
        s += __shfl_xor(s, m);
        q += __shfl_xor(q, m);
      }
      s4[mt][rg] = s;
      q4[mt][rg] = q;
    }
  }
  // last loop barrier already synchronized all waves; red (aliases Gs) is free
  if (l15 == 0) {
#pragma unroll
    for (int mt = 0; mt < 2; ++mt) {
      int cbase = wm * 32 + mt * 16 + quad * 4;
      *(f32x4*)(&red[wn * 128 + cbase]) = s4[mt];
      *(f32x4*)(&red[256 + wn * 128 + cbase]) = q4[mt];
    }
  }

  // ---- epilogue: transpose via LDS (reuse Xs as Os[p][XROW]) ----
  _Float16* Os = Xs;
#pragma unroll
  for (int mt = 0; mt < 2; ++mt)
#pragma unroll
    for (int nt = 0; nt < 8; ++nt) {
      f16x4 o4;
#pragma unroll
      for (int rg = 0; rg < 4; ++rg) o4[rg] = (_Float16)acc[mt][nt][rg];
      *(f16x4*)(&Os[(wn * 128 + nt * 16 + l15) * XROW + wm * 32 + mt * 16 + quad * 4]) = o4;
    }
  __syncthreads();

  if (tid < 128) {
    atomicAdd(&sums[tid], red[tid] + red[128 + tid]);
    atomicAdd(&sums[128 + tid], red[256 + tid] + red[384 + tid]);
  }
#pragma unroll
  for (int pass = 0; pass < 8; ++pass) {
    int r = pass * 32 + (tid >> 4);
    f16x8 v = *(const f16x8*)(&Os[r * XROW + ch * 8]);
    *(f16x8*)(Yout + ((size_t)b * Nn + p0 + r) * Cn + ch * 8) = v;
  }
}

// ---------------- final: scatter + BN2 affine + residual + relu ----------------
__global__ __launch_bounds__(256) void final_k(const _Float16* __restrict__ y2,
                                               const float* __restrict__ x,
                                               const int* __restrict__ reidx,
                                               const float* __restrict__ coeff,
                                               float* __restrict__ out) {
  __shared__ float ft[128 * FT];  // 33792 B
  int tid = threadIdx.x;
  int b = blockIdx.x >> 10;
  int n0 = (blockIdx.x & 1023) * 64;
  {
    int ch = tid & 15;
#pragma unroll
    for (int pass = 0; pass < 4; ++pass) {
      int r = pass * 16 + (tid >> 4);
      int m = reidx[(size_t)b * Nn + n0 + r];
      f16x8 v = *(const f16x8*)(y2 + ((size_t)b * Nn + m) * Cn + ch * 8);
#pragma unroll
      for (int k = 0; k < 8; ++k) ft[(ch * 8 + k) * FT + r] = (float)v[k];
    }
  }
  __syncthreads();
  int cc = tid >> 4;
  int j4 = (tid & 15) * 4;
#pragma unroll
  for (int pass = 0; pass < 8; ++pass) {
    int c = pass * 16 + cc;
    float a = coeff[c];
    float bb = coeff[128 + c];
    f32x2 v0 = *(const f32x2*)(&ft[c * FT + j4]);
    f32x2 v1 = *(const f32x2*)(&ft[c * FT + j4 + 2]);
    size_t gi = ((size_t)b * Cn + c) * Nn + n0 + j4;
    f32x4 xv = *(const f32x4*)(&x[gi]);
    f32x4 r;
    r.x = fmaxf(a * v0.x + bb + xv.x, 0.f);
    r.y = fmaxf(a * v0.y + bb + xv.y, 0.f);
    r.z = fmaxf(a * v1.x + bb + xv.z, 0.f);
    r.w = fmaxf(a * v1.y + bb + xv.w, 0.f);
    *(f32x4*)(&out[gi]) = r;
  }
}

extern "C" void kernel_launch(void* const* d_in, const int* in_sizes, int n_in,
                              void* d_out, int out_size, void* d_ws, size_t ws_size,
                              hipStream_t stream) {
  (void)in_sizes; (void)n_in; (void)out_size; (void)ws_size;
  const float* x = (const float*)d_in[0];
  const float* coords = (const float*)d_in[1];
  const int* indices = (const int*)d_in[2];
  const int* reindices = (const int*)d_in[3];
  const float* w1 = (const float*)d_in[4];
  const float* gamma1 = (const float*)d_in[5];
  const float* beta1 = (const float*)d_in[6];
  const float* w2 = (const float*)d_in[7];
  const float* gamma2 = (const float*)d_in[8];
  const float* beta2 = (const float*)d_in[9];
  float* out = (float*)d_out;

  // workspace: [0,64MB) xp -> y2 ; then sums1/sums2/coeff1/coeff2 ; then Wr f16
  char* ws = (char*)d_ws;
  const size_t BUF0 = (size_t)Bn * Nn * Cn * sizeof(_Float16);  // 64 MB
  _Float16* buf0 = (_Float16*)ws;
  float* sums1 = (float*)(ws + BUF0);
  float* sums2 = sums1 + 256;
  float* coeff1 = sums1 + 512;
  float* coeff2 = sums1 + 768;
  _Float16* Wr = (_Float16*)(ws + BUF0 + 4096);  // 2*9*128*128 f16 = 576 KB

  // d_out doubles as scratch until the final kernel: y1 f16 [0,64MB), G
  char* dob = (char*)d_out;
  _Float16* y1 = (_Float16*)dob;
  float* G = (float*)(dob + BUF0);  // 9 MB

  hipMemsetAsync(sums1, 0, 512 * sizeof(float), stream);

  repack_w<<<1152, 256, 0, stream>>>(w1, w2, Wr);
  gather_x<<<Bn * 1024, 256, 0, stream>>>(x, reindices, buf0);
  gather_g<<<Bn * 256, 256, 0, stream>>>(coords, indices, G);

  // A/B: conv1 = pure-LDS W-staged experiment, conv2 = r0-exact control
  conv_wlds<<<Bn * 256, 512, 0, stream>>>(buf0, Wr, G, y1, sums1);
  bncoeff<<<1, 128, 0, stream>>>(sums1, gamma1, beta1, coeff1);
  conv_mfma<1><<<Bn * 256, 256, 0, stream>>>(y1, Wr + (size_t)KT * Cn * Cn, G,
                                             buf0, sums2, coeff1);
  bncoeff<<<1, 128, 0, stream>>>(sums2, gamma2, beta2, coeff2);
  final_k<<<Bn * 1024, 256, 0, stream>>>(buf0, x, reindices, coeff2, out);
}

// Round 11
// 524.161 us; speedup vs baseline: 1.1883x; 1.0605x over previous
//
#include <hip/hip_runtime.h>

#define Bn 4
#define Cn 128
#define Nn 65536
#define KT 9
#define T_OUT 256
#define T_HALO 264
#define XROW 136        // f16 elems per LDS row (128 + 8 pad) = 272 B
#define GROW 264        // f16 elems per LDS G row
#define FT 66           // f32 transpose-tile row stride (dwords)

typedef _Float16 f16x8 __attribute__((ext_vector_type(8)));
typedef _Float16 f16x4 __attribute__((ext_vector_type(4)));
typedef float f32x4 __attribute__((ext_vector_type(4)));
typedef float f32x2 __attribute__((ext_vector_type(2)));

// ---------------- repack weights: [O][C][K] f32 -> [t][o][c] f16 ----------------
__global__ __launch_bounds__(256) void repack_w(const float* __restrict__ w1,
                                                const float* __restrict__ w2,
                                                _Float16* __restrict__ Wr) {
  int i = blockIdx.x * 256 + threadIdx.x;  // [cv][t][o][c], total 2*9*128*128
  int c = i & 127;
  int o = (i >> 7) & 127;
  int t = (i >> 14) % KT;
  int cv = i / (KT << 14);
  const float* w = cv ? w2 : w1;
  Wr[i] = (_Float16)w[(o * 128 + c) * KT + t];
}

// ---------------- gather x into curve order, f16, channel-contiguous rows ------
__global__ __launch_bounds__(256) void gather_x(const float* __restrict__ x,
                                                const int* __restrict__ reidx,
                                                _Float16* __restrict__ xp) {
  __shared__ float ft[128 * FT];  // 33792 B
  int tid = threadIdx.x;
  int b = blockIdx.x >> 10;
  int n0 = (blockIdx.x & 1023) * 64;
  const float* xb = x + (size_t)b * Cn * Nn;
  {
    int cc = tid >> 4;
    int j4 = (tid & 15) * 4;
#pragma unroll
    for (int pass = 0; pass < 8; ++pass) {
      int c = pass * 16 + cc;
      f32x4 v = *(const f32x4*)(&xb[(size_t)c * Nn + n0 + j4]);
      *(f32x2*)(&ft[c * FT + j4]) = f32x2{v.x, v.y};
      *(f32x2*)(&ft[c * FT + j4 + 2]) = f32x2{v.z, v.w};
    }
  }
  __syncthreads();
  int ch = tid & 15;
  int rr = tid >> 4;
#pragma unroll
  for (int pass = 0; pass < 4; ++pass) {
    int r = pass * 16 + rr;
    int m = reidx[(size_t)b * Nn + n0 + r];
    f16x8 v;
#pragma unroll
    for (int k = 0; k < 8; ++k) v[k] = (_Float16)ft[(ch * 8 + k) * FT + r];
    *(f16x8*)(xp + ((size_t)b * Nn + m) * Cn + ch * 8) = v;
  }
}

// ---------------- fused: gather coords (LDS) + gaussian tap weights ------------
__global__ __launch_bounds__(256) void gather_g(const float* __restrict__ coords,
                                                const int* __restrict__ indices,
                                                float* __restrict__ G) {
  __shared__ float cx[264], cy[264], cz[264];
  int tid = threadIdx.x;
  int b = blockIdx.x >> 8;
  int n0 = (blockIdx.x & 255) * 256;
  const float* cb = coords + (size_t)b * 3 * Nn;
  for (int i = tid; i < 264; i += 256) {
    int q = n0 - 4 + i;
    q = q < 0 ? 0 : (q > Nn - 1 ? Nn - 1 : q);  // OOB value irrelevant (x==0 there)
    int idx = indices[(size_t)b * Nn + q];
    cx[i] = cb[idx];
    cy[i] = cb[Nn + idx];
    cz[i] = cb[2 * Nn + idx];
  }
  __syncthreads();
  int m = n0 + tid;
  float x0 = cx[tid + 4], y0 = cy[tid + 4], z0 = cz[tid + 4];
  float* Gb = G + (size_t)b * KT * Nn;
#pragma unroll
  for (int t = 0; t < KT; ++t) {
    float dx = cx[tid + t] - x0;
    float dy = cy[tid + t] - y0;
    float dz = cz[tid + t] - z0;
    Gb[(size_t)t * Nn + m] = __expf(-(dx * dx + dy * dy + dz * dz));  // sigma=1
  }
}

// ---------------- BN affine coefficients ---------------------------------------
__global__ void bncoeff(const float* __restrict__ sums,
                        const float* __restrict__ gamma,
                        const float* __restrict__ beta,
                        float* __restrict__ coeff) {
  int c = threadIdx.x;  // 128 threads
  const float inv = 1.0f / (float)((size_t)Bn * Nn);
  float mean = sums[c] * inv;
  float var = sums[128 + c] * inv - mean * mean;
  float a = gamma[c] * rsqrtf(var + 1e-5f);
  coeff[c] = a;
  coeff[128 + c] = beta[c] - mean * a;
}

__device__ __forceinline__ f16x8 scale8(f16x8 v, _Float16 g) {
  f16x8 r;
#pragma unroll
  for (int i = 0; i < 8; ++i) r[i] = v[i] * g;  // 4x v_pk_mul_f16
  return r;
}

// ================= fused weighted conv: pure-LDS K-loop (r10 winner) ===========
// m97-structure: W staged per-tap into LDS (double-buffered, padded rows) so the
// K-loop issues ONLY ds_read/lgkmcnt ops (no vmcnt in the MFMA ladder). Prefetch
// tap t+2's W to regs at iteration top (latency hidden under compute), one
// barrier per tap, ds_write after the barrier. 512 thr = 8 waves (2/SIMD),
// waves 4(M)x2(N), per-wave M32 x N128 (A-reuse 8, acc 64 AGPR). LDS 146 KB ->
// 1 block/CU. Measured r10: ~125us vs 150us control (-17%).
// TRANS=1: fold BN1 affine + ReLU into the X staging loads (as the old control).
template <int TRANS>
__global__ __launch_bounds__(512) void conv_wlds(
    const _Float16* __restrict__ Xin, const _Float16* __restrict__ W,
    const float* __restrict__ G, _Float16* __restrict__ Yout,
    float* __restrict__ sums, const float* __restrict__ coeff) {
  __shared__ __align__(16) _Float16 Xs[T_HALO * XROW];       // 71808 B
  __shared__ __align__(16) _Float16 Wlds[2][128 * XROW];     // 2 x 34816 B
  __shared__ __align__(16) unsigned char aux[KT * GROW * 2]; // 4752 B: Gs / red
  _Float16* Gs = (_Float16*)aux;
  float* red = (float*)aux;

  const int tid = threadIdx.x;
  const int b = blockIdx.x >> 8;
  const int p0 = (blockIdx.x & 255) * T_OUT;
  const int ch = tid & 15;

  // ---- issue W0/W1 prefetch first (flies during X staging) ----
  f16x8 w0r[4], w1r[4];
#pragma unroll
  for (int i = 0; i < 4; ++i) {
    int q = i * 512 + tid;  // 16B chunk id, 2048 per tap
    w0r[i] = *(const f16x8*)(W + (q >> 4) * 128 + (q & 15) * 8);
    w1r[i] = *(const f16x8*)(W + 16384 + (q >> 4) * 128 + (q & 15) * 8);
  }

  // ---- stage X halo tile (512 thr: 32 rows/pass), optional BN1+ReLU ----
#pragma unroll
  for (int pass = 0; pass < 9; ++pass) {
    int r = pass * 32 + (tid >> 4);
    if (r < T_HALO) {
      int q = p0 - 4 + r;
      f16x8 v = {0, 0, 0, 0, 0, 0, 0, 0};
      if (q >= 0 && q < Nn) {
        v = *(const f16x8*)(Xin + ((size_t)b * Nn + q) * Cn + ch * 8);
        if (TRANS) {
#pragma unroll
          for (int i = 0; i < 8; ++i) {
            float f = fmaxf(coeff[ch * 8 + i] * (float)v[i] + coeff[128 + ch * 8 + i], 0.f);
            v[i] = (_Float16)f;
          }
        }
      }
      *(f16x8*)(&Xs[r * XROW + ch * 8]) = v;
    }
  }
  // ---- stage G ----
  {
    const float* gb = G + (size_t)b * KT * Nn + p0;
    for (int i = tid; i < KT * 256; i += 512) {
      int t = i >> 8;
      int p = i & 255;
      Gs[t * GROW + p] = (_Float16)gb[(size_t)t * Nn + p];
    }
  }
  // ---- write W0/W1 into padded LDS rows ----
#pragma unroll
  for (int i = 0; i < 4; ++i) {
    int q = i * 512 + tid;
    *(f16x8*)(&Wlds[0][(q >> 4) * XROW + (q & 15) * 8]) = w0r[i];
    *(f16x8*)(&Wlds[1][(q >> 4) * XROW + (q & 15) * 8]) = w1r[i];
  }

  const int w = tid >> 6;        // 0..7
  const int lane = tid & 63;
  const int l15 = lane & 15;
  const int quad = lane >> 4;
  const int wm = w >> 1;         // 0..3: channels wm*32 .. +31
  const int wn = w & 1;          // 0..1: positions wn*128 .. +127

  f32x4 acc[2][8];
  const f32x4 z4 = {0.f, 0.f, 0.f, 0.f};
#pragma unroll
  for (int mt = 0; mt < 2; ++mt)
#pragma unroll
    for (int nt = 0; nt < 8; ++nt) acc[mt][nt] = z4;

  __syncthreads();

  // ---- K-loop: pure-LDS ladder; W dbuf with reg prefetch of tap t+2 ----
  f16x8 wpre[4];
#pragma unroll 1
  for (int t = 0; t < KT; ++t) {
    if (t <= KT - 3) {
      const _Float16* Wt2 = W + ((size_t)(t + 2) << 14);
#pragma unroll
      for (int i = 0; i < 4; ++i) {
        int q = i * 512 + tid;
        wpre[i] = *(const f16x8*)(Wt2 + (q >> 4) * 128 + (q & 15) * 8);
      }
    }

    _Float16 gt[8];
#pragma unroll
    for (int nt = 0; nt < 8; ++nt)
      gt[nt] = Gs[t * GROW + wn * 128 + nt * 16 + l15];

    const _Float16* Wb = &Wlds[t & 1][0];
#pragma unroll
    for (int ko = 0; ko < 4; ++ko) {
      f16x8 a2[2];
#pragma unroll
      for (int mt = 0; mt < 2; ++mt)
        a2[mt] = *(const f16x8*)(Wb + (wm * 32 + mt * 16 + l15) * XROW + ko * 32 + quad * 8);
#pragma unroll
      for (int nt = 0; nt < 8; ++nt) {
        f16x8 bv = *(const f16x8*)(&Xs[(wn * 128 + nt * 16 + l15 + t) * XROW + ko * 32 + quad * 8]);
        bv = scale8(bv, gt[nt]);
#pragma unroll
        for (int mt = 0; mt < 2; ++mt)
          acc[mt][nt] = __builtin_amdgcn_mfma_f32_16x16x32_f16(a2[mt], bv, acc[mt][nt], 0, 0, 0);
      }
    }

    __syncthreads();  // all waves done reading Wlds[t&1]; prefetch loads drained
    if (t <= KT - 3) {
#pragma unroll
      for (int i = 0; i < 4; ++i) {
        int q = i * 512 + tid;
        *(f16x8*)(&Wlds[t & 1][(q >> 4) * XROW + (q & 15) * 8]) = wpre[i];
      }
    }
    // tap t+1 reads Wlds[(t+1)&1] (untouched); tap t+2's reads happen after
    // barrier(t+1), which makes these writes visible. No extra barrier needed.
  }

  // ---- BN partial sums (shfl tree over l15) ----
  // channel of acc[mt][*][rg] = wm*32 + mt*16 + quad*4 + rg
  f32x4 s4[2], q4[2];
#pragma unroll
  for (int mt = 0; mt < 2; ++mt) {
#pragma unroll
    for (int rg = 0; rg < 4; ++rg) {
      float s = 0.f, q = 0.f;
#pragma unroll
      for (int nt = 0; nt < 8; ++nt) {
        float v = acc[mt][nt][rg];
        s += v;
        q += v * v;
      }
#pragma unroll
      for (int m = 1; m < 16; m <<= 1) {
        s += __shfl_xor(s, m);
        q += __shfl_xor(q, m);
      }
      s4[mt][rg] = s;
      q4[mt][rg] = q;
    }
  }
  // last loop barrier already synchronized all waves; red (aliases Gs) is free
  if (l15 == 0) {
#pragma unroll
    for (int mt = 0; mt < 2; ++mt) {
      int cbase = wm * 32 + mt * 16 + quad * 4;
      *(f32x4*)(&red[wn * 128 + cbase]) = s4[mt];
      *(f32x4*)(&red[256 + wn * 128 + cbase]) = q4[mt];
    }
  }

  // ---- epilogue: transpose via LDS (reuse Xs as Os[p][XROW]) ----
  _Float16* Os = Xs;
#pragma unroll
  for (int mt = 0; mt < 2; ++mt)
#pragma unroll
    for (int nt = 0; nt < 8; ++nt) {
      f16x4 o4;
#pragma unroll
      for (int rg = 0; rg < 4; ++rg) o4[rg] = (_Float16)acc[mt][nt][rg];
      *(f16x4*)(&Os[(wn * 128 + nt * 16 + l15) * XROW + wm * 32 + mt * 16 + quad * 4]) = o4;
    }
  __syncthreads();

  if (tid < 128) {
    atomicAdd(&sums[tid], red[tid] + red[128 + tid]);
    atomicAdd(&sums[128 + tid], red[256 + tid] + red[384 + tid]);
  }
#pragma unroll
  for (int pass = 0; pass < 8; ++pass) {
    int r = pass * 32 + (tid >> 4);
    f16x8 v = *(const f16x8*)(&Os[r * XROW + ch * 8]);
    *(f16x8*)(Yout + ((size_t)b * Nn + p0 + r) * Cn + ch * 8) = v;
  }
}

// ---------------- final: scatter + BN2 affine + residual + relu ----------------
__global__ __launch_bounds__(256) void final_k(const _Float16* __restrict__ y2,
                                               const float* __restrict__ x,
                                               const int* __restrict__ reidx,
                                               const float* __restrict__ coeff,
                                               float* __restrict__ out) {
  __shared__ float ft[128 * FT];  // 33792 B
  int tid = threadIdx.x;
  int b = blockIdx.x >> 10;
  int n0 = (blockIdx.x & 1023) * 64;
  {
    int ch = tid & 15;
#pragma unroll
    for (int pass = 0; pass < 4; ++pass) {
      int r = pass * 16 + (tid >> 4);
      int m = reidx[(size_t)b * Nn + n0 + r];
      f16x8 v = *(const f16x8*)(y2 + ((size_t)b * Nn + m) * Cn + ch * 8);
#pragma unroll
      for (int k = 0; k < 8; ++k) ft[(ch * 8 + k) * FT + r] = (float)v[k];
    }
  }
  __syncthreads();
  int cc = tid >> 4;
  int j4 = (tid & 15) * 4;
#pragma unroll
  for (int pass = 0; pass < 8; ++pass) {
    int c = pass * 16 + cc;
    float a = coeff[c];
    float bb = coeff[128 + c];
    f32x2 v0 = *(const f32x2*)(&ft[c * FT + j4]);
    f32x2 v1 = *(const f32x2*)(&ft[c * FT + j4 + 2]);
    size_t gi = ((size_t)b * Cn + c) * Nn + n0 + j4;
    f32x4 xv = *(const f32x4*)(&x[gi]);
    f32x4 r;
    r.x = fmaxf(a * v0.x + bb + xv.x, 0.f);
    r.y = fmaxf(a * v0.y + bb + xv.y, 0.f);
    r.z = fmaxf(a * v1.x + bb + xv.z, 0.f);
    r.w = fmaxf(a * v1.y + bb + xv.w, 0.f);
    *(f32x4*)(&out[gi]) = r;
  }
}

extern "C" void kernel_launch(void* const* d_in, const int* in_sizes, int n_in,
                              void* d_out, int out_size, void* d_ws, size_t ws_size,
                              hipStream_t stream) {
  (void)in_sizes; (void)n_in; (void)out_size; (void)ws_size;
  const float* x = (const float*)d_in[0];
  const float* coords = (const float*)d_in[1];
  const int* indices = (const int*)d_in[2];
  const int* reindices = (const int*)d_in[3];
  const float* w1 = (const float*)d_in[4];
  const float* gamma1 = (const float*)d_in[5];
  const float* beta1 = (const float*)d_in[6];
  const float* w2 = (const float*)d_in[7];
  const float* gamma2 = (const float*)d_in[8];
  const float* beta2 = (const float*)d_in[9];
  float* out = (float*)d_out;

  // workspace: [0,64MB) xp -> y2 ; then sums1/sums2/coeff1/coeff2 ; then Wr f16
  char* ws = (char*)d_ws;
  const size_t BUF0 = (size_t)Bn * Nn * Cn * sizeof(_Float16);  // 64 MB
  _Float16* buf0 = (_Float16*)ws;
  float* sums1 = (float*)(ws + BUF0);
  float* sums2 = sums1 + 256;
  float* coeff1 = sums1 + 512;
  float* coeff2 = sums1 + 768;
  _Float16* Wr = (_Float16*)(ws + BUF0 + 4096);  // 2*9*128*128 f16 = 576 KB

  // d_out doubles as scratch until the final kernel: y1 f16 [0,64MB), G
  char* dob = (char*)d_out;
  _Float16* y1 = (_Float16*)dob;
  float* G = (float*)(dob + BUF0);  // 9 MB

  hipMemsetAsync(sums1, 0, 512 * sizeof(float), stream);

  repack_w<<<1152, 256, 0, stream>>>(w1, w2, Wr);
  gather_x<<<Bn * 1024, 256, 0, stream>>>(x, reindices, buf0);
  gather_g<<<Bn * 256, 256, 0, stream>>>(coords, indices, G);

  // r10 winner rolled out to BOTH convs (TRANS=1 folds BN1+ReLU into staging)
  conv_wlds<0><<<Bn * 256, 512, 0, stream>>>(buf0, Wr, G, y1, sums1, nullptr);
  bncoeff<<<1, 128, 0, stream>>>(sums1, gamma1, beta1, coeff1);
  conv_wlds<1><<<Bn * 256, 512, 0, stream>>>(y1, Wr + (size_t)KT * Cn * Cn, G,
                                             buf0, sums2, coeff1);
  bncoeff<<<1, 128, 0, stream>>>(sums2, gamma2, beta2, coeff2);
  final_k<<<Bn * 1024, 256, 0, stream>>>(buf0, x, reindices, coeff2, out);
}

// Round 12
// 517.797 us; speedup vs baseline: 1.2029x; 1.0123x over previous
//
#include <hip/hip_runtime.h>

#define Bn 4
#define Cn 128
#define Nn 65536
#define KT 9
#define T_OUT 256
#define T_HALO 264
#define XROW 136        // f16 elems per LDS X row (128 + 8 pad) = 272 B
#define GROW 264        // f16 elems per LDS G row
#define FT 66           // f32 transpose-tile row stride (dwords)

typedef _Float16 f16x8 __attribute__((ext_vector_type(8)));
typedef _Float16 f16x4 __attribute__((ext_vector_type(4)));
typedef float f32x4 __attribute__((ext_vector_type(4)));
typedef float f32x2 __attribute__((ext_vector_type(2)));

// ---------------- repack weights: [O][C][K] f32 -> fragment-linear f16 ---------
// Layout [cv][t][wm][ko][mt][lane][8]: the exact order conv_wlds' waves read A
// fragments, so both LDS staging writes and K-loop A-reads are lane*16B linear
// (canonical conflict-free). wm in {0,1} (M64 per group), mt in {0..3},
// ko in {0..3}, lane = quad*16+l15. Channel o = wm*64+mt*16+l15,
// k-col c = ko*32+quad*8+j.
__global__ __launch_bounds__(256) void repack_w(const float* __restrict__ w1,
                                                const float* __restrict__ w2,
                                                _Float16* __restrict__ Wr) {
  int i = blockIdx.x * 256 + threadIdx.x;  // total 2*9*16384
  int j = i & 7;
  int lane = (i >> 3) & 63;
  int mt = (i >> 9) & 3;
  int ko = (i >> 11) & 3;
  int wm = (i >> 13) & 1;
  int t = (i >> 14) % KT;
  int cv = i / (KT << 14);
  int o = wm * 64 + mt * 16 + (lane & 15);
  int c = ko * 32 + (lane >> 4) * 8 + j;
  const float* w = cv ? w2 : w1;
  Wr[i] = (_Float16)w[(o * 128 + c) * KT + t];
}

// ---------------- gather x into curve order, f16, channel-contiguous rows ------
__global__ __launch_bounds__(256) void gather_x(const float* __restrict__ x,
                                                const int* __restrict__ reidx,
                                                _Float16* __restrict__ xp) {
  __shared__ float ft[128 * FT];  // 33792 B
  int tid = threadIdx.x;
  int b = blockIdx.x >> 10;
  int n0 = (blockIdx.x & 1023) * 64;
  const float* xb = x + (size_t)b * Cn * Nn;
  {
    int cc = tid >> 4;
    int j4 = (tid & 15) * 4;
#pragma unroll
    for (int pass = 0; pass < 8; ++pass) {
      int c = pass * 16 + cc;
      f32x4 v = *(const f32x4*)(&xb[(size_t)c * Nn + n0 + j4]);
      *(f32x2*)(&ft[c * FT + j4]) = f32x2{v.x, v.y};
      *(f32x2*)(&ft[c * FT + j4 + 2]) = f32x2{v.z, v.w};
    }
  }
  __syncthreads();
  int ch = tid & 15;
  int rr = tid >> 4;
#pragma unroll
  for (int pass = 0; pass < 4; ++pass) {
    int r = pass * 16 + rr;
    int m = reidx[(size_t)b * Nn + n0 + r];
    f16x8 v;
#pragma unroll
    for (int k = 0; k < 8; ++k) v[k] = (_Float16)ft[(ch * 8 + k) * FT + r];
    *(f16x8*)(xp + ((size_t)b * Nn + m) * Cn + ch * 8) = v;
  }
}

// ---------------- fused: gather coords (LDS) + gaussian tap weights ------------
__global__ __launch_bounds__(256) void gather_g(const float* __restrict__ coords,
                                                const int* __restrict__ indices,
                                                float* __restrict__ G) {
  __shared__ float cx[264], cy[264], cz[264];
  int tid = threadIdx.x;
  int b = blockIdx.x >> 8;
  int n0 = (blockIdx.x & 255) * 256;
  const float* cb = coords + (size_t)b * 3 * Nn;
  for (int i = tid; i < 264; i += 256) {
    int q = n0 - 4 + i;
    q = q < 0 ? 0 : (q > Nn - 1 ? Nn - 1 : q);  // OOB value irrelevant (x==0 there)
    int idx = indices[(size_t)b * Nn + q];
    cx[i] = cb[idx];
    cy[i] = cb[Nn + idx];
    cz[i] = cb[2 * Nn + idx];
  }
  __syncthreads();
  int m = n0 + tid;
  float x0 = cx[tid + 4], y0 = cy[tid + 4], z0 = cz[tid + 4];
  float* Gb = G + (size_t)b * KT * Nn;
#pragma unroll
  for (int t = 0; t < KT; ++t) {
    float dx = cx[tid + t] - x0;
    float dy = cy[tid + t] - y0;
    float dz = cz[tid + t] - z0;
    Gb[(size_t)t * Nn + m] = __expf(-(dx * dx + dy * dy + dz * dz));  // sigma=1
  }
}

// ---------------- BN affine coefficients ---------------------------------------
__global__ void bncoeff(const float* __restrict__ sums,
                        const float* __restrict__ gamma,
                        const float* __restrict__ beta,
                        float* __restrict__ coeff) {
  int c = threadIdx.x;  // 128 threads
  const float inv = 1.0f / (float)((size_t)Bn * Nn);
  float mean = sums[c] * inv;
  float var = sums[128 + c] * inv - mean * mean;
  float a = gamma[c] * rsqrtf(var + 1e-5f);
  coeff[c] = a;
  coeff[128 + c] = beta[c] - mean * a;
}

__device__ __forceinline__ f16x8 scale8(f16x8 v, _Float16 g) {
  f16x8 r;
#pragma unroll
  for (int i = 0; i < 8; ++i) r[i] = v[i] * g;  // 4x v_pk_mul_f16
  return r;
}

// ================= fused weighted conv: pure-LDS K-loop (r10/r11 winner) =======
// r12 changes (r11 PMC: LDS ~65% busy, conflicts 12.58M, VALU 28%):
//  (1) Wlds fragment-linear: staging writes and A-reads are lane*16B linear ->
//      zero W bank conflicts; no pad, Wlds = 2x32KB.
//  (2) Wave geometry 2(M)x4(N), per-wave M64 x N64: LDS reads/tap 40->32,
//      scale8 per tap 32->16 (VALU pk_mul halved), MFMA count unchanged,
//      acc stays 64 AGPR. (r8's failure of this geometry was the (512,4)
//      spill cap, absent here: plain launch_bounds(512), r11 measured 88 VGPR.)
// Structure otherwise identical: W dbuf in LDS, reg prefetch of tap t+2,
// one barrier per tap, pure ds_read ladder.
template <int TRANS>
__global__ __launch_bounds__(512) void conv_wlds(
    const _Float16* __restrict__ Xin, const _Float16* __restrict__ W,
    const float* __restrict__ G, _Float16* __restrict__ Yout,
    float* __restrict__ sums, const float* __restrict__ coeff) {
  __shared__ __align__(16) _Float16 Xs[T_HALO * XROW];       // 71808 B
  __shared__ __align__(16) _Float16 Wlds[2][16384];          // 2 x 32768 B
  __shared__ __align__(16) unsigned char aux[KT * GROW * 2]; // 4752 B: Gs / red
  _Float16* Gs = (_Float16*)aux;
  float* red = (float*)aux;   // s: [0,512) q: [512,1024) f32

  const int tid = threadIdx.x;
  const int b = blockIdx.x >> 8;
  const int p0 = (blockIdx.x & 255) * T_OUT;
  const int ch = tid & 15;

  // ---- issue W0/W1 prefetch first (flies during X staging) ----
  f16x8 w0r[4], w1r[4];
#pragma unroll
  for (int i = 0; i < 4; ++i) {
    int q = i * 512 + tid;  // 16B chunk id, 2048 per tap
    w0r[i] = *(const f16x8*)(W + q * 8);
    w1r[i] = *(const f16x8*)(W + 16384 + q * 8);
  }

  // ---- stage X halo tile (512 thr: 32 rows/pass), optional BN1+ReLU ----
#pragma unroll
  for (int pass = 0; pass < 9; ++pass) {
    int r = pass * 32 + (tid >> 4);
    if (r < T_HALO) {
      int q = p0 - 4 + r;
      f16x8 v = {0, 0, 0, 0, 0, 0, 0, 0};
      if (q >= 0 && q < Nn) {
        v = *(const f16x8*)(Xin + ((size_t)b * Nn + q) * Cn + ch * 8);
        if (TRANS) {
#pragma unroll
          for (int i = 0; i < 8; ++i) {
            float f = fmaxf(coeff[ch * 8 + i] * (float)v[i] + coeff[128 + ch * 8 + i], 0.f);
            v[i] = (_Float16)f;
          }
        }
      }
      *(f16x8*)(&Xs[r * XROW + ch * 8]) = v;
    }
  }
  // ---- stage G ----
  {
    const float* gb = G + (size_t)b * KT * Nn + p0;
    for (int i = tid; i < KT * 256; i += 512) {
      int t = i >> 8;
      int p = i & 255;
      Gs[t * GROW + p] = (_Float16)gb[(size_t)t * Nn + p];
    }
  }
  // ---- write W0/W1 into LDS, lane-linear ----
#pragma unroll
  for (int i = 0; i < 4; ++i) {
    int q = i * 512 + tid;
    *(f16x8*)(&Wlds[0][q * 8]) = w0r[i];
    *(f16x8*)(&Wlds[1][q * 8]) = w1r[i];
  }

  const int w = tid >> 6;        // 0..7
  const int lane = tid & 63;
  const int l15 = lane & 15;
  const int quad = lane >> 4;
  const int wm = w >> 2;         // 0..1: channels wm*64 .. +63
  const int wn = w & 3;          // 0..3: positions wn*64 .. +63

  f32x4 acc[4][4];
  const f32x4 z4 = {0.f, 0.f, 0.f, 0.f};
#pragma unroll
  for (int mt = 0; mt < 4; ++mt)
#pragma unroll
    for (int nt = 0; nt < 4; ++nt) acc[mt][nt] = z4;

  __syncthreads();

  // ---- K-loop: pure-LDS ladder; W dbuf with reg prefetch of tap t+2 ----
  f16x8 wpre[4];
#pragma unroll 1
  for (int t = 0; t < KT; ++t) {
    if (t <= KT - 3) {
      const _Float16* Wt2 = W + ((size_t)(t + 2) << 14);
#pragma unroll
      for (int i = 0; i < 4; ++i) {
        int q = i * 512 + tid;
        wpre[i] = *(const f16x8*)(Wt2 + q * 8);
      }
    }

    _Float16 gt[4];
#pragma unroll
    for (int nt = 0; nt < 4; ++nt)
      gt[nt] = Gs[t * GROW + wn * 64 + nt * 16 + l15];

    const _Float16* Wb = &Wlds[t & 1][wm * 8192];
#pragma unroll
    for (int ko = 0; ko < 4; ++ko) {
      f16x8 a4[4];
#pragma unroll
      for (int mt = 0; mt < 4; ++mt)
        a4[mt] = *(const f16x8*)(Wb + ko * 2048 + mt * 512 + lane * 8);
#pragma unroll
      for (int nt = 0; nt < 4; ++nt) {
        f16x8 bv = *(const f16x8*)(&Xs[(wn * 64 + nt * 16 + l15 + t) * XROW + ko * 32 + quad * 8]);
        bv = scale8(bv, gt[nt]);
#pragma unroll
        for (int mt = 0; mt < 4; ++mt)
          acc[mt][nt] = __builtin_amdgcn_mfma_f32_16x16x32_f16(a4[mt], bv, acc[mt][nt], 0, 0, 0);
      }
    }

    __syncthreads();  // all waves done reading Wlds[t&1]; prefetch loads drained
    if (t <= KT - 3) {
#pragma unroll
      for (int i = 0; i < 4; ++i) {
        int q = i * 512 + tid;
        *(f16x8*)(&Wlds[t & 1][q * 8]) = wpre[i];
      }
    }
    // tap t+1 reads Wlds[(t+1)&1] (untouched); tap t+2's reads happen after
    // barrier(t+1), which makes these writes visible. No extra barrier needed.
  }

  // ---- BN partial sums (shfl tree over l15) ----
  // channel of acc[mt][*][rg] = wm*64 + mt*16 + quad*4 + rg
  f32x4 s4[4], q4[4];
#pragma unroll
  for (int mt = 0; mt < 4; ++mt) {
#pragma unroll
    for (int rg = 0; rg < 4; ++rg) {
      float s = 0.f, q = 0.f;
#pragma unroll
      for (int nt = 0; nt < 4; ++nt) {
        float v = acc[mt][nt][rg];
        s += v;
        q += v * v;
      }
#pragma unroll
      for (int m = 1; m < 16; m <<= 1) {
        s += __shfl_xor(s, m);
        q += __shfl_xor(q, m);
      }
      s4[mt][rg] = s;
      q4[mt][rg] = q;
    }
  }
  // last loop barrier already synchronized all waves; red (aliases Gs) is free
  if (l15 == 0) {
#pragma unroll
    for (int mt = 0; mt < 4; ++mt) {
      int cbase = wm * 64 + mt * 16 + quad * 4;
      *(f32x4*)(&red[wn * 128 + cbase]) = s4[mt];         // s: [0,512)
      *(f32x4*)(&red[512 + wn * 128 + cbase]) = q4[mt];   // q: [512,1024)
    }
  }

  // ---- epilogue: transpose via LDS (reuse Xs as Os[p][XROW]) ----
  _Float16* Os = Xs;
#pragma unroll
  for (int mt = 0; mt < 4; ++mt)
#pragma unroll
    for (int nt = 0; nt < 4; ++nt) {
      f16x4 o4;
#pragma unroll
      for (int rg = 0; rg < 4; ++rg) o4[rg] = (_Float16)acc[mt][nt][rg];
      *(f16x4*)(&Os[(wn * 64 + nt * 16 + l15) * XROW + wm * 64 + mt * 16 + quad * 4]) = o4;
    }
  __syncthreads();

  if (tid < 128) {
    atomicAdd(&sums[tid],
              red[tid] + red[128 + tid] + red[256 + tid] + red[384 + tid]);
    atomicAdd(&sums[128 + tid],
              red[512 + tid] + red[640 + tid] + red[768 + tid] + red[896 + tid]);
  }
#pragma unroll
  for (int pass = 0; pass < 8; ++pass) {
    int r = pass * 32 + (tid >> 4);
    f16x8 v = *(const f16x8*)(&Os[r * XROW + ch * 8]);
    *(f16x8*)(Yout + ((size_t)b * Nn + p0 + r) * Cn + ch * 8) = v;
  }
}

// ---------------- final: scatter + BN2 affine + residual + relu ----------------
__global__ __launch_bounds__(256) void final_k(const _Float16* __restrict__ y2,
                                               const float* __restrict__ x,
                                               const int* __restrict__ reidx,
                                               const float* __restrict__ coeff,
                                               float* __restrict__ out) {
  __shared__ float ft[128 * FT];  // 33792 B
  int tid = threadIdx.x;
  int b = blockIdx.x >> 10;
  int n0 = (blockIdx.x & 1023) * 64;
  {
    int ch = tid & 15;
#pragma unroll
    for (int pass = 0; pass < 4; ++pass) {
      int r = pass * 16 + (tid >> 4);
      int m = reidx[(size_t)b * Nn + n0 + r];
      f16x8 v = *(const f16x8*)(y2 + ((size_t)b * Nn + m) * Cn + ch * 8);
#pragma unroll
      for (int k = 0; k < 8; ++k) ft[(ch * 8 + k) * FT + r] = (float)v[k];
    }
  }
  __syncthreads();
  int cc = tid >> 4;
  int j4 = (tid & 15) * 4;
#pragma unroll
  for (int pass = 0; pass < 8; ++pass) {
    int c = pass * 16 + cc;
    float a = coeff[c];
    float bb = coeff[128 + c];
    f32x2 v0 = *(const f32x2*)(&ft[c * FT + j4]);
    f32x2 v1 = *(const f32x2*)(&ft[c * FT + j4 + 2]);
    size_t gi = ((size_t)b * Cn + c) * Nn + n0 + j4;
    f32x4 xv = *(const f32x4*)(&x[gi]);
    f32x4 r;
    r.x = fmaxf(a * v0.x + bb + xv.x, 0.f);
    r.y = fmaxf(a * v0.y + bb + xv.y, 0.f);
    r.z = fmaxf(a * v1.x + bb + xv.z, 0.f);
    r.w = fmaxf(a * v1.y + bb + xv.w, 0.f);
    *(f32x4*)(&out[gi]) = r;
  }
}

extern "C" void kernel_launch(void* const* d_in, const int* in_sizes, int n_in,
                              void* d_out, int out_size, void* d_ws, size_t ws_size,
                              hipStream_t stream) {
  (void)in_sizes; (void)n_in; (void)out_size; (void)ws_size;
  const float* x = (const float*)d_in[0];
  const float* coords = (const float*)d_in[1];
  const int* indices = (const int*)d_in[2];
  const int* reindices = (const int*)d_in[3];
  const float* w1 = (const float*)d_in[4];
  const float* gamma1 = (const float*)d_in[5];
  const float* beta1 = (const float*)d_in[6];
  const float* w2 = (const float*)d_in[7];
  const float* gamma2 = (const float*)d_in[8];
  const float* beta2 = (const float*)d_in[9];
  float* out = (float*)d_out;

  // workspace: [0,64MB) xp -> y2 ; then sums1/sums2/coeff1/coeff2 ; then Wr f16
  char* ws = (char*)d_ws;
  const size_t BUF0 = (size_t)Bn * Nn * Cn * sizeof(_Float16);  // 64 MB
  _Float16* buf0 = (_Float16*)ws;
  float* sums1 = (float*)(ws + BUF0);
  float* sums2 = sums1 + 256;
  float* coeff1 = sums1 + 512;
  float* coeff2 = sums1 + 768;
  _Float16* Wr = (_Float16*)(ws + BUF0 + 4096);  // 2*9*128*128 f16 = 576 KB

  // d_out doubles as scratch until the final kernel: y1 f16 [0,64MB), G
  char* dob = (char*)d_out;
  _Float16* y1 = (_Float16*)dob;
  float* G = (float*)(dob + BUF0);  // 9 MB

  hipMemsetAsync(sums1, 0, 512 * sizeof(float), stream);

  repack_w<<<1152, 256, 0, stream>>>(w1, w2, Wr);
  gather_x<<<Bn * 1024, 256, 0, stream>>>(x, reindices, buf0);
  gather_g<<<Bn * 256, 256, 0, stream>>>(coords, indices, G);

  conv_wlds<0><<<Bn * 256, 512, 0, stream>>>(buf0, Wr, G, y1, sums1, nullptr);
  bncoeff<<<1, 128, 0, stream>>>(sums1, gamma1, beta1, coeff1);
  conv_wlds<1><<<Bn * 256, 512, 0, stream>>>(y1, Wr + (size_t)KT * Cn * Cn, G,
                                             buf0, sums2, coeff1);
  bncoeff<<<1, 128, 0, stream>>>(sums2, gamma2, beta2, coeff2);
  final_k<<<Bn * 1024, 256, 0, stream>>>(buf0, x, reindices, coeff2, out);
}

// Round 13
// 514.541 us; speedup vs baseline: 1.2105x; 1.0063x over previous
//
#include <hip/hip_runtime.h>

#define Bn 4
#define Cn 128
#define Nn 65536
#define KT 9
#define T_OUT 256
#define T_HALO 264
#define XROW 136        // f16 elems per LDS X row (128 + 8 pad) = 272 B
#define GROW 264        // f16 elems per LDS G row
#define FT 65           // f32 transpose-tile row stride (dwords); 65 = 64+1 pad
                        // (was 66: stage-2 reads were 8-way bank conflicts;
                        //  65 gives 2-way writes / 4-way reads)

typedef _Float16 f16x8 __attribute__((ext_vector_type(8)));
typedef _Float16 f16x4 __attribute__((ext_vector_type(4)));
typedef float f32x4 __attribute__((ext_vector_type(4)));
typedef float f32x2 __attribute__((ext_vector_type(2)));

// ---------------- repack weights: [O][C][K] f32 -> fragment-linear f16 ---------
// Layout [cv][t][wm][ko][mt][lane][8] (see conv_wlds A-read order).
__global__ __launch_bounds__(256) void repack_w(const float* __restrict__ w1,
                                                const float* __restrict__ w2,
                                                _Float16* __restrict__ Wr) {
  int i = blockIdx.x * 256 + threadIdx.x;  // total 2*9*16384
  int j = i & 7;
  int lane = (i >> 3) & 63;
  int mt = (i >> 9) & 3;
  int ko = (i >> 11) & 3;
  int wm = (i >> 13) & 1;
  int t = (i >> 14) % KT;
  int cv = i / (KT << 14);
  int o = wm * 64 + mt * 16 + (lane & 15);
  int c = ko * 32 + (lane >> 4) * 8 + j;
  const float* w = cv ? w2 : w1;
  Wr[i] = (_Float16)w[(o * 128 + c) * KT + t];
}

// ---------------- transpose x -> n-ordered f16 rows (NO scatter) ---------------
// r13: the curve-order scatter moved into conv1's staging (hidden under
// compute); this kernel is now coalesced on both sides.
__global__ __launch_bounds__(256) void gather_x(const float* __restrict__ x,
                                                _Float16* __restrict__ xp) {
  __shared__ float ft[128 * FT];  // 33280 B
  int tid = threadIdx.x;
  int b = blockIdx.x >> 10;
  int n0 = (blockIdx.x & 1023) * 64;
  const float* xb = x + (size_t)b * Cn * Nn;
  {
    int cc = tid >> 4;
    int j4 = (tid & 15) * 4;
#pragma unroll
    for (int pass = 0; pass < 8; ++pass) {
      int c = pass * 16 + cc;
      f32x4 v = *(const f32x4*)(&xb[(size_t)c * Nn + n0 + j4]);
      *(f32x2*)(&ft[c * FT + j4]) = f32x2{v.x, v.y};
      *(f32x2*)(&ft[c * FT + j4 + 2]) = f32x2{v.z, v.w};
    }
  }
  __syncthreads();
  int ch = tid & 15;
  int rr = tid >> 4;
#pragma unroll
  for (int pass = 0; pass < 4; ++pass) {
    int r = pass * 16 + rr;
    f16x8 v;
#pragma unroll
    for (int k = 0; k < 8; ++k) v[k] = (_Float16)ft[(ch * 8 + k) * FT + r];
    *(f16x8*)(xp + ((size_t)b * Nn + n0 + r) * Cn + ch * 8) = v;
  }
}

// ---------------- fused: gather coords (LDS) + gaussian tap weights ------------
__global__ __launch_bounds__(256) void gather_g(const float* __restrict__ coords,
                                                const int* __restrict__ indices,
                                                float* __restrict__ G) {
  __shared__ float cx[264], cy[264], cz[264];
  int tid = threadIdx.x;
  int b = blockIdx.x >> 8;
  int n0 = (blockIdx.x & 255) * 256;
  const float* cb = coords + (size_t)b * 3 * Nn;
  for (int i = tid; i < 264; i += 256) {
    int q = n0 - 4 + i;
    q = q < 0 ? 0 : (q > Nn - 1 ? Nn - 1 : q);  // OOB value irrelevant (x==0 there)
    int idx = indices[(size_t)b * Nn + q];
    cx[i] = cb[idx];
    cy[i] = cb[Nn + idx];
    cz[i] = cb[2 * Nn + idx];
  }
  __syncthreads();
  int m = n0 + tid;
  float x0 = cx[tid + 4], y0 = cy[tid + 4], z0 = cz[tid + 4];
  float* Gb = G + (size_t)b * KT * Nn;
#pragma unroll
  for (int t = 0; t < KT; ++t) {
    float dx = cx[tid + t] - x0;
    float dy = cy[tid + t] - y0;
    float dz = cz[tid + t] - z0;
    Gb[(size_t)t * Nn + m] = __expf(-(dx * dx + dy * dy + dz * dz));  // sigma=1
  }
}

// ---------------- BN affine coefficients ---------------------------------------
__global__ void bncoeff(const float* __restrict__ sums,
                        const float* __restrict__ gamma,
                        const float* __restrict__ beta,
                        float* __restrict__ coeff) {
  int c = threadIdx.x;  // 128 threads
  const float inv = 1.0f / (float)((size_t)Bn * Nn);
  float mean = sums[c] * inv;
  float var = sums[128 + c] * inv - mean * mean;
  float a = gamma[c] * rsqrtf(var + 1e-5f);
  coeff[c] = a;
  coeff[128 + c] = beta[c] - mean * a;
}

__device__ __forceinline__ f16x8 scale8(f16x8 v, _Float16 g) {
  f16x8 r;
#pragma unroll
  for (int i = 0; i < 8; ++i) r[i] = v[i] * g;  // 4x v_pk_mul_f16
  return r;
}

// ================= fused weighted conv: pure-LDS K-loop ========================
// r13: GATHER=1 (conv1) stages X via indices (absorbs gather_x's scatter);
// SCATTER=1 (conv2) writes output rows to indices[m] (absorbs final_k's
// gather). Both scattered 256B accesses hide under the compute-bound loop.
// Otherwise the r12 structure: fragment-linear Wlds dbuf, reg prefetch of tap
// t+2, one barrier per tap, waves 2(M)x4(N) per-wave M64xN64, acc 64 AGPR.
template <int TRANS, int GATHER, int SCATTER>
__global__ __launch_bounds__(512) void conv_wlds(
    const _Float16* __restrict__ Xin, const _Float16* __restrict__ W,
    const float* __restrict__ G, const int* __restrict__ idxmap,
    _Float16* __restrict__ Yout, float* __restrict__ sums,
    const float* __restrict__ coeff) {
  __shared__ __align__(16) _Float16 Xs[T_HALO * XROW];       // 71808 B
  __shared__ __align__(16) _Float16 Wlds[2][16384];          // 2 x 32768 B
  __shared__ __align__(16) unsigned char aux[KT * GROW * 2]; // 4752 B: Gs / red
  _Float16* Gs = (_Float16*)aux;
  float* red = (float*)aux;   // s: [0,512) q: [512,1024) f32

  const int tid = threadIdx.x;
  const int b = blockIdx.x >> 8;
  const int p0 = (blockIdx.x & 255) * T_OUT;
  const int ch = tid & 15;

  // ---- issue W0/W1 prefetch first (flies during X staging) ----
  f16x8 w0r[4], w1r[4];
#pragma unroll
  for (int i = 0; i < 4; ++i) {
    int q = i * 512 + tid;  // 16B chunk id, 2048 per tap
    w0r[i] = *(const f16x8*)(W + q * 8);
    w1r[i] = *(const f16x8*)(W + 16384 + q * 8);
  }

  // ---- stage X halo tile (512 thr: 32 rows/pass), optional gather/BN1+ReLU ----
#pragma unroll
  for (int pass = 0; pass < 9; ++pass) {
    int r = pass * 32 + (tid >> 4);
    if (r < T_HALO) {
      int q = p0 - 4 + r;
      f16x8 v = {0, 0, 0, 0, 0, 0, 0, 0};
      if (q >= 0 && q < Nn) {
        int src = GATHER ? idxmap[(size_t)b * Nn + q] : q;
        v = *(const f16x8*)(Xin + ((size_t)b * Nn + src) * Cn + ch * 8);
        if (TRANS) {
#pragma unroll
          for (int i = 0; i < 8; ++i) {
            float f = fmaxf(coeff[ch * 8 + i] * (float)v[i] + coeff[128 + ch * 8 + i], 0.f);
            v[i] = (_Float16)f;
          }
        }
      }
      *(f16x8*)(&Xs[r * XROW + ch * 8]) = v;
    }
  }
  // ---- stage G ----
  {
    const float* gb = G + (size_t)b * KT * Nn + p0;
    for (int i = tid; i < KT * 256; i += 512) {
      int t = i >> 8;
      int p = i & 255;
      Gs[t * GROW + p] = (_Float16)gb[(size_t)t * Nn + p];
    }
  }
  // ---- write W0/W1 into LDS, lane-linear ----
#pragma unroll
  for (int i = 0; i < 4; ++i) {
    int q = i * 512 + tid;
    *(f16x8*)(&Wlds[0][q * 8]) = w0r[i];
    *(f16x8*)(&Wlds[1][q * 8]) = w1r[i];
  }

  const int w = tid >> 6;        // 0..7
  const int lane = tid & 63;
  const int l15 = lane & 15;
  const int quad = lane >> 4;
  const int wm = w >> 2;         // 0..1: channels wm*64 .. +63
  const int wn = w & 3;          // 0..3: positions wn*64 .. +63

  f32x4 acc[4][4];
  const f32x4 z4 = {0.f, 0.f, 0.f, 0.f};
#pragma unroll
  for (int mt = 0; mt < 4; ++mt)
#pragma unroll
    for (int nt = 0; nt < 4; ++nt) acc[mt][nt] = z4;

  __syncthreads();

  // ---- K-loop: pure-LDS ladder; W dbuf with reg prefetch of tap t+2 ----
  f16x8 wpre[4];
#pragma unroll 1
  for (int t = 0; t < KT; ++t) {
    if (t <= KT - 3) {
      const _Float16* Wt2 = W + ((size_t)(t + 2) << 14);
#pragma unroll
      for (int i = 0; i < 4; ++i) {
        int q = i * 512 + tid;
        wpre[i] = *(const f16x8*)(Wt2 + q * 8);
      }
    }

    _Float16 gt[4];
#pragma unroll
    for (int nt = 0; nt < 4; ++nt)
      gt[nt] = Gs[t * GROW + wn * 64 + nt * 16 + l15];

    const _Float16* Wb = &Wlds[t & 1][wm * 8192];
#pragma unroll
    for (int ko = 0; ko < 4; ++ko) {
      f16x8 a4[4];
#pragma unroll
      for (int mt = 0; mt < 4; ++mt)
        a4[mt] = *(const f16x8*)(Wb + ko * 2048 + mt * 512 + lane * 8);
#pragma unroll
      for (int nt = 0; nt < 4; ++nt) {
        f16x8 bv = *(const f16x8*)(&Xs[(wn * 64 + nt * 16 + l15 + t) * XROW + ko * 32 + quad * 8]);
        bv = scale8(bv, gt[nt]);
#pragma unroll
        for (int mt = 0; mt < 4; ++mt)
          acc[mt][nt] = __builtin_amdgcn_mfma_f32_16x16x32_f16(a4[mt], bv, acc[mt][nt], 0, 0, 0);
      }
    }

    __syncthreads();  // all waves done reading Wlds[t&1]; prefetch loads drained
    if (t <= KT - 3) {
#pragma unroll
      for (int i = 0; i < 4; ++i) {
        int q = i * 512 + tid;
        *(f16x8*)(&Wlds[t & 1][q * 8]) = wpre[i];
      }
    }
  }

  // ---- BN partial sums (shfl tree over l15) ----
  // channel of acc[mt][*][rg] = wm*64 + mt*16 + quad*4 + rg
  f32x4 s4[4], q4[4];
#pragma unroll
  for (int mt = 0; mt < 4; ++mt) {
#pragma unroll
    for (int rg = 0; rg < 4; ++rg) {
      float s = 0.f, q = 0.f;
#pragma unroll
      for (int nt = 0; nt < 4; ++nt) {
        float v = acc[mt][nt][rg];
        s += v;
        q += v * v;
      }
#pragma unroll
      for (int m = 1; m < 16; m <<= 1) {
        s += __shfl_xor(s, m);
        q += __shfl_xor(q, m);
      }
      s4[mt][rg] = s;
      q4[mt][rg] = q;
    }
  }
  // last loop barrier already synchronized all waves; red (aliases Gs) is free
  if (l15 == 0) {
#pragma unroll
    for (int mt = 0; mt < 4; ++mt) {
      int cbase = wm * 64 + mt * 16 + quad * 4;
      *(f32x4*)(&red[wn * 128 + cbase]) = s4[mt];         // s: [0,512)
      *(f32x4*)(&red[512 + wn * 128 + cbase]) = q4[mt];   // q: [512,1024)
    }
  }

  // ---- epilogue: transpose via LDS (reuse Xs as Os[p][XROW]) ----
  _Float16* Os = Xs;
#pragma unroll
  for (int mt = 0; mt < 4; ++mt)
#pragma unroll
    for (int nt = 0; nt < 4; ++nt) {
      f16x4 o4;
#pragma unroll
      for (int rg = 0; rg < 4; ++rg) o4[rg] = (_Float16)acc[mt][nt][rg];
      *(f16x4*)(&Os[(wn * 64 + nt * 16 + l15) * XROW + wm * 64 + mt * 16 + quad * 4]) = o4;
    }
  __syncthreads();

  if (tid < 128) {
    atomicAdd(&sums[tid],
              red[tid] + red[128 + tid] + red[256 + tid] + red[384 + tid]);
    atomicAdd(&sums[128 + tid],
              red[512 + tid] + red[640 + tid] + red[768 + tid] + red[896 + tid]);
  }
#pragma unroll
  for (int pass = 0; pass < 8; ++pass) {
    int r = pass * 32 + (tid >> 4);
    f16x8 v = *(const f16x8*)(&Os[r * XROW + ch * 8]);
    int dst = SCATTER ? idxmap[(size_t)b * Nn + p0 + r] : (p0 + r);
    *(f16x8*)(Yout + ((size_t)b * Nn + dst) * Cn + ch * 8) = v;
  }
}

// ---------------- final: BN2 affine + residual + relu (NO gather) --------------
// r13: conv2 scattered y2 into n-order, so stage-1 reads are sequential.
__global__ __launch_bounds__(256) void final_k(const _Float16* __restrict__ y2,
                                               const float* __restrict__ x,
                                               const float* __restrict__ coeff,
                                               float* __restrict__ out) {
  __shared__ float ft[128 * FT];  // 33280 B
  int tid = threadIdx.x;
  int b = blockIdx.x >> 10;
  int n0 = (blockIdx.x & 1023) * 64;
  {
    int ch = tid & 15;
#pragma unroll
    for (int pass = 0; pass < 4; ++pass) {
      int r = pass * 16 + (tid >> 4);
      f16x8 v = *(const f16x8*)(y2 + ((size_t)b * Nn + n0 + r) * Cn + ch * 8);
#pragma unroll
      for (int k = 0; k < 8; ++k) ft[(ch * 8 + k) * FT + r] = (float)v[k];
    }
  }
  __syncthreads();
  int cc = tid >> 4;
  int j4 = (tid & 15) * 4;
#pragma unroll
  for (int pass = 0; pass < 8; ++pass) {
    int c = pass * 16 + cc;
    float a = coeff[c];
    float bb = coeff[128 + c];
    f32x2 v0 = *(const f32x2*)(&ft[c * FT + j4]);
    f32x2 v1 = *(const f32x2*)(&ft[c * FT + j4 + 2]);
    size_t gi = ((size_t)b * Cn + c) * Nn + n0 + j4;
    f32x4 xv = *(const f32x4*)(&x[gi]);
    f32x4 r;
    r.x = fmaxf(a * v0.x + bb + xv.x, 0.f);
    r.y = fmaxf(a * v0.y + bb + xv.y, 0.f);
    r.z = fmaxf(a * v1.x + bb + xv.z, 0.f);
    r.w = fmaxf(a * v1.y + bb + xv.w, 0.f);
    *(f32x4*)(&out[gi]) = r;
  }
}

extern "C" void kernel_launch(void* const* d_in, const int* in_sizes, int n_in,
                              void* d_out, int out_size, void* d_ws, size_t ws_size,
                              hipStream_t stream) {
  (void)in_sizes; (void)n_in; (void)out_size; (void)ws_size;
  const float* x = (const float*)d_in[0];
  const float* coords = (const float*)d_in[1];
  const int* indices = (const int*)d_in[2];
  const float* w1 = (const float*)d_in[4];
  const float* gamma1 = (const float*)d_in[5];
  const float* beta1 = (const float*)d_in[6];
  const float* w2 = (const float*)d_in[7];
  const float* gamma2 = (const float*)d_in[8];
  const float* beta2 = (const float*)d_in[9];
  float* out = (float*)d_out;

  // workspace: [0,64MB) xp -> y2s ; then sums1/sums2/coeff1/coeff2 ; then Wr f16
  char* ws = (char*)d_ws;
  const size_t BUF0 = (size_t)Bn * Nn * Cn * sizeof(_Float16);  // 64 MB
  _Float16* buf0 = (_Float16*)ws;
  float* sums1 = (float*)(ws + BUF0);
  float* sums2 = sums1 + 256;
  float* coeff1 = sums1 + 512;
  float* coeff2 = sums1 + 768;
  _Float16* Wr = (_Float16*)(ws + BUF0 + 4096);  // 2*9*128*128 f16 = 576 KB

  // d_out doubles as scratch until the final kernel: y1 f16 [0,64MB), G
  char* dob = (char*)d_out;
  _Float16* y1 = (_Float16*)dob;
  float* G = (float*)(dob + BUF0);  // 9 MB

  hipMemsetAsync(sums1, 0, 512 * sizeof(float), stream);

  repack_w<<<1152, 256, 0, stream>>>(w1, w2, Wr);
  gather_x<<<Bn * 1024, 256, 0, stream>>>(x, buf0);
  gather_g<<<Bn * 256, 256, 0, stream>>>(coords, indices, G);

  // conv1: gathers x rows via indices (curve staging); writes y1 curve-dense.
  conv_wlds<0, 1, 0><<<Bn * 256, 512, 0, stream>>>(buf0, Wr, G, indices, y1,
                                                   sums1, nullptr);
  bncoeff<<<1, 128, 0, stream>>>(sums1, gamma1, beta1, coeff1);
  // conv2: reads y1 curve-dense; scatters output rows to n-order via indices.
  conv_wlds<1, 0, 1><<<Bn * 256, 512, 0, stream>>>(y1, Wr + (size_t)KT * Cn * Cn,
                                                   G, indices, buf0, sums2, coeff1);
  bncoeff<<<1, 128, 0, stream>>>(sums2, gamma2, beta2, coeff2);
  final_k<<<Bn * 1024, 256, 0, stream>>>(buf0, x, coeff2, out);
}